// Round 2
// baseline (338.086 us; speedup 1.0000x reference)
//
#include <hip/hip_runtime.h>

#define BB 2
#define HH 64
#define WWD 64
#define CCH 256
#define GG 8
#define KPT 9
#define HCC 32
#define PP 4096
#define C3 768

// ---------------- generic tiled GEMM: C = A(MxK) * B(KxN) + bias ----------------
__global__ __launch_bounds__(256) void gemm_bias(const float* __restrict__ A,
        const float* __restrict__ Bm, const float* __restrict__ bias,
        float* __restrict__ Cout, int M, int Kd, int N) {
    __shared__ float As[64][17];
    __shared__ float Bs[16][65];
    int tid = threadIdx.x;
    int row0 = blockIdx.x * 64;
    int col0 = blockIdx.y * 64;
    int ty = tid >> 4, tx = tid & 15;
    float acc[4][4] = {};
    for (int k0 = 0; k0 < Kd; k0 += 16) {
        #pragma unroll
        for (int q = 0; q < 4; q++) {
            int idx = tid + q * 256;
            int r = idx >> 4, c = idx & 15;
            As[r][c] = A[(row0 + r) * Kd + k0 + c];
        }
        #pragma unroll
        for (int q = 0; q < 4; q++) {
            int idx = tid + q * 256;
            int r = idx >> 6, c = idx & 63;
            Bs[r][c] = Bm[(k0 + r) * N + col0 + c];
        }
        __syncthreads();
        #pragma unroll
        for (int kk = 0; kk < 16; kk++) {
            float a[4], b[4];
            #pragma unroll
            for (int i = 0; i < 4; i++) a[i] = As[ty*4+i][kk];
            #pragma unroll
            for (int j = 0; j < 4; j++) b[j] = Bs[kk][tx*4+j];
            #pragma unroll
            for (int i = 0; i < 4; i++)
                #pragma unroll
                for (int j = 0; j < 4; j++) acc[i][j] += a[i]*b[j];
        }
        __syncthreads();
    }
    #pragma unroll
    for (int i = 0; i < 4; i++) {
        int r = row0 + ty*4 + i;
        #pragma unroll
        for (int j = 0; j < 4; j++) {
            int c = col0 + tx*4 + j;
            Cout[r * N + c] = acc[i][j] + bias[c];
        }
    }
}

// ---------------- depthwise 3x3 conv (SAME) on (B,H,W,768) ----------------
__global__ __launch_bounds__(256) void dwconv(const float* __restrict__ qkv,
        const float* __restrict__ dww, const float* __restrict__ dwb,
        float* __restrict__ out) {
    int idx = blockIdx.x * 256 + threadIdx.x;
    int ch = idx % C3;
    int pix = idx / C3;
    int w = pix % WWD, h = (pix / WWD) % HH, b = pix / (HH*WWD);
    float acc = dwb[ch];
    #pragma unroll
    for (int ky = 0; ky < 3; ky++) {
        int hh = h + ky - 1;
        if (hh < 0 || hh >= HH) continue;
        #pragma unroll
        for (int kx = 0; kx < 3; kx++) {
            int ww_ = w + kx - 1;
            if (ww_ < 0 || ww_ >= WWD) continue;
            acc += qkv[((b*HH+hh)*WWD+ww_)*C3 + ch] * dww[(ky*3+kx)*C3 + ch];
        }
    }
    out[idx] = acc;
}

// ------------- composite offset/mask weights: fold pconv + linear -------------
// cwT layout: [768][160]  (k-index major; k<576: (patch*64+i), k>=576: dense j)
// outputs o: 0..143 = offsets (g=o/18, oo=o%18), 144..152 = mask, 153..159 pad
__global__ void make_cw(const float* __restrict__ off_pconv_w,
        const float* __restrict__ off_w, const float* __restrict__ off_b,
        const float* __restrict__ mask_pconv_w, const float* __restrict__ mask_w,
        const float* __restrict__ mask_b, float* __restrict__ cwT,
        float* __restrict__ cb) {
    int k = blockIdx.x;      // 0..767
    int o = threadIdx.x;     // 0..159
    float val = 0.f;
    if (o < 153) {
        if (k < 576) {
            int patch = k >> 6, i = k & 63;
            if (o < 144) {
                int g = o / 18, oo = o % 18;
                for (int c = 0; c < 64; c++)
                    val += off_w[(g*18+oo)*256 + c] *
                           off_pconv_w[((g*64 + c)*64 + i)*9 + patch];
            } else {
                int oo = o - 144;
                for (int c = 0; c < 64; c++)
                    val += mask_w[oo*256 + c] * mask_pconv_w[(c*64 + i)*9 + patch];
            }
        } else {
            int j = k - 576;
            if (o < 144) {
                int g = o / 18, oo = o % 18;
                val = off_w[(g*18+oo)*256 + 64 + j];
            } else {
                val = mask_w[(o-144)*256 + 64 + j];
            }
        }
    }
    cwT[k*160 + o] = val;
    if (k == 0) {
        float bv = 0.f;
        if (o < 144) {
            int g = o / 18, oo = o % 18;
            const float PTSf[18] = {-1,-1,-1,0,-1,1,0,-1,0,0,0,1,1,-1,1,0,1,1};
            bv = off_b[g*18+oo] + PTSf[oo] * (float)(2*g+1);
        } else if (o < 153) {
            bv = mask_b[o-144];
        }
        cb[o] = bv;
    }
}

// ------------- im2col GEMM: per pixel 768 feats -> 153 outputs -------------
__global__ __launch_bounds__(256) void offmask_gemm(const float* __restrict__ qdw,
        const float* __restrict__ cwT, const float* __restrict__ cb,
        float* __restrict__ offmask) {
    __shared__ float fT[32][65];    // pixels x kk
    __shared__ float wT[64][160];   // kk x outputs
    int tid = threadIdx.x;
    int p0 = blockIdx.x * 32;
    int ty = tid >> 5, tx = tid & 31;   // ty 0..7, tx 0..31
    float acc[4][5] = {};
    for (int k0 = 0; k0 < 768; k0 += 64) {
        // load feature tile (im2col on the fly)
        #pragma unroll
        for (int q = 0; q < 8; q++) {
            int idx = tid + q * 256;
            int pl = idx >> 6, kk = idx & 63;
            int pixel = p0 + pl;
            int w = pixel & 63, h = (pixel >> 6) & 63, b = pixel >> 12;
            float v;
            if (k0 < 576) {
                int patch = k0 >> 6;
                int dy = patch / 3 - 1, dx = patch % 3 - 1;
                int hh = h + dy, ww_ = w + dx;
                v = (hh >= 0 && hh < 64 && ww_ >= 0 && ww_ < 64)
                    ? qdw[((b*64+hh)*64+ww_)*C3 + kk] : 0.f;
            } else {
                v = qdw[((b*64+h)*64+w)*C3 + 64 + (k0 - 576) + kk];
            }
            fT[pl][kk] = v;
        }
        // load weight tile
        #pragma unroll
        for (int q = 0; q < 40; q++) {
            int idx = tid + q * 256;
            int r = idx / 160, c = idx % 160;
            wT[r][c] = cwT[(k0 + r)*160 + c];
        }
        __syncthreads();
        #pragma unroll
        for (int kk = 0; kk < 64; kk++) {
            float a[4], b[5];
            #pragma unroll
            for (int i = 0; i < 4; i++) a[i] = fT[ty + 8*i][kk];
            #pragma unroll
            for (int j = 0; j < 5; j++) b[j] = wT[kk][tx + 32*j];
            #pragma unroll
            for (int i = 0; i < 4; i++)
                #pragma unroll
                for (int j = 0; j < 5; j++) acc[i][j] += a[i]*b[j];
        }
        __syncthreads();
    }
    #pragma unroll
    for (int i = 0; i < 4; i++) {
        int pixel = p0 + ty + 8*i;
        #pragma unroll
        for (int j = 0; j < 5; j++) {
            int c = tx + 32*j;
            if (c < 153) offmask[pixel*160 + c] = acc[i][j] + cb[c];
        }
    }
}

// ------------- deformable gather + softmax + weighted V sum -------------
__global__ __launch_bounds__(256) void deform_attn(const float* __restrict__ qdw,
        const float* __restrict__ offmask, float* __restrict__ attn_out) {
    int tid = threadIdx.x;
    int unit = blockIdx.x * 8 + (tid >> 5);
    int lane = tid & 31;
    int b = unit / (GG*PP);
    int rem = unit % (GG*PP);
    int g = rem / PP;
    int p = rem % PP;
    int w = p & 63, h = p >> 6;
    const float scale = 0.17677669529663687f;  // 32^-0.5
    float qv = qdw[((b*64+h)*64+w)*C3 + g*HCC + lane] * scale;
    const float* om = offmask + (b*PP + p) * 160;
    float logit[KPT], vs[KPT];
    #pragma unroll
    for (int k_ = 0; k_ < KPT; k_++) {
        float dx = om[g*18 + 2*k_];
        float dy = om[g*18 + 2*k_ + 1];
        float cx = fminf(fmaxf((float)w + dx, 0.f), 63.f);
        float cy = fminf(fmaxf((float)h + dy, 0.f), 63.f);
        float x0f = floorf(cx), y0f = floorf(cy);
        float wx = cx - x0f, wy = cy - y0f;
        int x0 = (int)x0f, y0 = (int)y0f;
        int x1 = min(x0 + 1, 63), y1 = min(y0 + 1, 63);
        int ch_k = 256 + g*HCC + lane;
        int ch_v = 512 + g*HCC + lane;
        int b00 = ((b*64+y0)*64+x0)*C3;
        int b01 = ((b*64+y0)*64+x1)*C3;
        int b10 = ((b*64+y1)*64+x0)*C3;
        int b11 = ((b*64+y1)*64+x1)*C3;
        float w00 = (1.f-wx)*(1.f-wy), w01 = wx*(1.f-wy);
        float w10 = (1.f-wx)*wy,       w11 = wx*wy;
        float kk = qdw[b00+ch_k]*w00 + qdw[b01+ch_k]*w01
                 + qdw[b10+ch_k]*w10 + qdw[b11+ch_k]*w11;
        float vv = qdw[b00+ch_v]*w00 + qdw[b01+ch_v]*w01
                 + qdw[b10+ch_v]*w10 + qdw[b11+ch_v]*w11;
        float m = om[144 + k_];
        float part = qv * kk;
        part += __shfl_xor(part, 16);
        part += __shfl_xor(part, 8);
        part += __shfl_xor(part, 4);
        part += __shfl_xor(part, 2);
        part += __shfl_xor(part, 1);
        logit[k_] = part * m;
        vs[k_] = vv * m;
    }
    float mx = logit[0];
    #pragma unroll
    for (int k_ = 1; k_ < KPT; k_++) mx = fmaxf(mx, logit[k_]);
    float s = 0.f, e[KPT];
    #pragma unroll
    for (int k_ = 0; k_ < KPT; k_++) { e[k_] = expf(logit[k_] - mx); s += e[k_]; }
    float inv = 1.f / s;
    float outv = 0.f;
    #pragma unroll
    for (int k_ = 0; k_ < KPT; k_++) outv += e[k_] * vs[k_];
    attn_out[(b*PP + p)*CCH + g*HCC + lane] = outv * inv;
}

extern "C" void kernel_launch(void* const* d_in, const int* in_sizes, int n_in,
                              void* d_out, int out_size, void* d_ws, size_t ws_size,
                              hipStream_t stream) {
    const float* x            = (const float*)d_in[0];
    const float* qkv_w        = (const float*)d_in[1];
    const float* qkv_b        = (const float*)d_in[2];
    const float* dw_w         = (const float*)d_in[3];
    const float* dw_b         = (const float*)d_in[4];
    const float* off_pconv_w  = (const float*)d_in[5];
    const float* off_w        = (const float*)d_in[6];
    const float* off_b        = (const float*)d_in[7];
    const float* mask_pconv_w = (const float*)d_in[8];
    const float* mask_w       = (const float*)d_in[9];
    const float* mask_b       = (const float*)d_in[10];
    const float* proj_w       = (const float*)d_in[11];
    const float* proj_b       = (const float*)d_in[12];

    float* ws       = (float*)d_ws;
    float* qkv      = ws;                       // 8192*768
    float* qdw      = qkv + 8192*768;           // 8192*768
    float* cwT      = qdw + 8192*768;           // 768*160
    float* cb       = cwT + 768*160;            // 160
    float* offmask  = cb + 160;                 // 8192*160
    float* attn_out = offmask + 8192*160;       // 8192*256

    // 1) qkv = x @ qkv_w + qkv_b
    gemm_bias<<<dim3(128, 12), 256, 0, stream>>>(x, qkv_w, qkv_b, qkv, 8192, 256, 768);
    // 2) depthwise 3x3
    dwconv<<<24576, 256, 0, stream>>>(qkv, dw_w, dw_b, qdw);
    // 3) composite offset/mask weights
    make_cw<<<768, 160, 0, stream>>>(off_pconv_w, off_w, off_b,
                                     mask_pconv_w, mask_w, mask_b, cwT, cb);
    // 4) offsets + mask via im2col GEMM
    offmask_gemm<<<256, 256, 0, stream>>>(qdw, cwT, cb, offmask);
    // 5) deformable attention
    deform_attn<<<8192, 256, 0, stream>>>(qdw, offmask, attn_out);
    // 6) projection
    gemm_bias<<<dim3(128, 4), 256, 0, stream>>>(attn_out, proj_w, proj_b,
                                                (float*)d_out, 8192, 256, 256);
}

// Round 8
// 198.977 us; speedup vs baseline: 1.6991x; 1.6991x over previous
//
#include <hip/hip_runtime.h>

typedef unsigned short u16;
typedef short bf16x8 __attribute__((ext_vector_type(8)));  // 8 bf16 (4 VGPRs)
typedef float f32x4 __attribute__((ext_vector_type(4)));

#define PP 4096
#define KPT 9

__device__ __forceinline__ u16 f2b(float f) {
    union { float f; unsigned int u; } v; v.f = f;
    unsigned int u = v.u;
    unsigned int r = u + 0x7FFFu + ((u >> 16) & 1u);   // RNE
    return (u16)(r >> 16);
}
__device__ __forceinline__ float b2f(u16 b) {
    union { unsigned int u; float f; } v; v.u = ((unsigned int)b) << 16;
    return v.f;
}

// ---- convert x (copy), qkv_w & proj_w (transpose) to bf16 ----
__global__ __launch_bounds__(256) void convert_inputs(
        const float* __restrict__ x, const float* __restrict__ qkv_w,
        const float* __restrict__ proj_w,
        u16* __restrict__ x_b, u16* __restrict__ qkv_wT_b, u16* __restrict__ proj_wT_b) {
    int idx = blockIdx.x * 256 + threadIdx.x;
    if (idx < 2097152) { x_b[idx] = f2b(x[idx]); return; }
    int i2 = idx - 2097152;
    if (i2 < 196608) {                       // qkv_w [256][768] -> T [768][256]
        int r = i2 / 768, c = i2 % 768;
        qkv_wT_b[c * 256 + r] = f2b(qkv_w[i2]);
        return;
    }
    int i3 = i2 - 196608;                    // proj_w [256][256] -> T
    int r = i3 >> 8, c = i3 & 255;
    proj_wT_b[c * 256 + r] = f2b(proj_w[i3]);
}

// ---- generic MFMA GEMM: out = A[M][K] * BT[N][K]^T + bias ----
// BM=128, BN=64, BK=32, 256 threads (4 waves, 2x2), wave tile 64x32
template<bool OUT_BF16>
__global__ __launch_bounds__(256) void mfma_gemm(
        const u16* __restrict__ A, const u16* __restrict__ BT,
        const float* __restrict__ bias, void* __restrict__ out,
        int M, int N, int K) {
    __shared__ u16 As[128][40];
    __shared__ u16 Bs[64][40];
    int tid = threadIdx.x;
    int row0 = blockIdx.x * 128, col0 = blockIdx.y * 64;
    int wid = tid >> 6, lane = tid & 63;
    int wr = wid >> 1, wc = wid & 1;
    int l15 = lane & 15, lhi = lane >> 4;
    f32x4 acc[4][2] = {};
    for (int k0 = 0; k0 < K; k0 += 32) {
        #pragma unroll
        for (int q = 0; q < 2; q++) {
            int idx = tid + q * 256;
            int r = idx >> 2, kc = (idx & 3) * 8;
            *(bf16x8*)&As[r][kc] = *(const bf16x8*)&A[(size_t)(row0 + r) * K + k0 + kc];
        }
        {
            int r = tid >> 2, kc = (tid & 3) * 8;
            *(bf16x8*)&Bs[r][kc] = *(const bf16x8*)&BT[(size_t)(col0 + r) * K + k0 + kc];
        }
        __syncthreads();
        bf16x8 bfr[2];
        #pragma unroll
        for (int j = 0; j < 2; j++)
            bfr[j] = *(const bf16x8*)&Bs[wc * 32 + j * 16 + l15][lhi * 8];
        #pragma unroll
        for (int i = 0; i < 4; i++) {
            bf16x8 afr = *(const bf16x8*)&As[wr * 64 + i * 16 + l15][lhi * 8];
            #pragma unroll
            for (int j = 0; j < 2; j++)
                acc[i][j] = __builtin_amdgcn_mfma_f32_16x16x32_bf16(afr, bfr[j], acc[i][j], 0, 0, 0);
        }
        __syncthreads();
    }
    #pragma unroll
    for (int i = 0; i < 4; i++) {
        int row = row0 + wr * 64 + i * 16 + lhi * 4;
        #pragma unroll
        for (int j = 0; j < 2; j++) {
            int col = col0 + wc * 32 + j * 16 + l15;
            float bv = bias[col];
            #pragma unroll
            for (int r = 0; r < 4; r++) {
                float v = acc[i][j][r] + bv;
                if (OUT_BF16) ((u16*)out)[(size_t)(row + r) * N + col] = f2b(v);
                else          ((float*)out)[(size_t)(row + r) * N + col] = v;
            }
        }
    }
}

// ---- depthwise 3x3 (SAME), bf16 in/out, fp32 accum, 8 ch/thread ----
__global__ __launch_bounds__(256) void dwconv_b(const u16* __restrict__ qkv_b,
        const float* __restrict__ dww, const float* __restrict__ dwb,
        u16* __restrict__ out) {
    int idx = blockIdx.x * 256 + threadIdx.x;       // 8192*96
    int c8 = (idx % 96) * 8;
    int pix = idx / 96;
    int w = pix & 63, h = (pix >> 6) & 63, b = pix >> 12;
    float acc[8];
    #pragma unroll
    for (int j = 0; j < 8; j++) acc[j] = dwb[c8 + j];
    #pragma unroll
    for (int ky = 0; ky < 3; ky++) {
        int hh = h + ky - 1;
        if (hh < 0 || hh >= 64) continue;
        #pragma unroll
        for (int kx = 0; kx < 3; kx++) {
            int ww = w + kx - 1;
            if (ww < 0 || ww >= 64) continue;
            bf16x8 v = *(const bf16x8*)&qkv_b[((size_t)((b * 64 + hh) * 64 + ww)) * 768 + c8];
            #pragma unroll
            for (int j = 0; j < 8; j++)
                acc[j] += b2f((u16)v[j]) * dww[(ky * 3 + kx) * 768 + c8 + j];
        }
    }
    bf16x8 o;
    #pragma unroll
    for (int j = 0; j < 8; j++) o[j] = (short)f2b(acc[j]);
    *(bf16x8*)&out[(size_t)idx * 8] = o;
}

// ---- composite offset/mask weights (fold pconv + linear), bf16 transposed ----
// cwT_b layout: [160][768]  (o-major). o: 0..143 offsets, 144..152 mask, rest 0.
__global__ void make_cw(const float* __restrict__ off_pconv_w,
        const float* __restrict__ off_w, const float* __restrict__ off_b,
        const float* __restrict__ mask_pconv_w, const float* __restrict__ mask_w,
        const float* __restrict__ mask_b, u16* __restrict__ cwT_b,
        float* __restrict__ cb) {
    int k = blockIdx.x;      // 0..767
    int o = threadIdx.x;     // 0..159
    float val = 0.f;
    if (o < 153) {
        if (k < 576) {
            int patch = k >> 6, i = k & 63;
            if (o < 144) {
                int g = o / 18, oo = o % 18;
                for (int c = 0; c < 64; c++)
                    val += off_w[(g * 18 + oo) * 256 + c] *
                           off_pconv_w[((g * 64 + c) * 64 + i) * 9 + patch];
            } else {
                int oo = o - 144;
                for (int c = 0; c < 64; c++)
                    val += mask_w[oo * 256 + c] * mask_pconv_w[(c * 64 + i) * 9 + patch];
            }
        } else {
            int j = k - 576;
            if (o < 144) {
                int g = o / 18, oo = o % 18;
                val = off_w[(g * 18 + oo) * 256 + 64 + j];
            } else {
                val = mask_w[(o - 144) * 256 + 64 + j];
            }
        }
    }
    cwT_b[o * 768 + k] = f2b(val);
    if (k == 0) {
        float bv = 0.f;
        if (o < 144) {
            int g = o / 18, oo = o % 18;
            const float PTSf[18] = {-1,-1,-1,0,-1,1,0,-1,0,0,0,1,1,-1,1,0,1,1};
            bv = off_b[g * 18 + oo] + PTSf[oo] * (float)(2 * g + 1);
        } else if (o < 153) {
            bv = mask_b[o - 144];
        }
        cb[o] = bv;
    }
}

// ---- offsets+mask via im2col MFMA GEMM: M=8192(32/blk) K=768 N=160 ----
__global__ __launch_bounds__(256) void offmask_mfma(const u16* __restrict__ qdw_b,
        const u16* __restrict__ cwT_b, const float* __restrict__ cb,
        float* __restrict__ offmask) {
    __shared__ u16 As[32][40];
    __shared__ u16 Bs[160][40];
    int tid = threadIdx.x;
    int p0 = blockIdx.x * 32;
    int wid = tid >> 6, lane = tid & 63;
    int wr = wid >> 1, wc = wid & 1;
    int l15 = lane & 15, lhi = lane >> 4;
    f32x4 acc[5] = {};
    for (int k0 = 0; k0 < 768; k0 += 32) {
        if (tid < 128) {
            int r = tid >> 2, kc = (tid & 3) * 8;
            int pixel = p0 + r;
            int w = pixel & 63, h = (pixel >> 6) & 63, b = pixel >> 12;
            bf16x8 v = {};
            if (k0 < 576) {
                int patch = k0 >> 6;
                int dy = patch / 3 - 1, dx = patch % 3 - 1;
                int hh = h + dy, ww = w + dx;
                if (hh >= 0 && hh < 64 && ww >= 0 && ww < 64)
                    v = *(const bf16x8*)&qdw_b[((size_t)((b * 64 + hh) * 64 + ww)) * 768 + (k0 & 63) + kc];
            } else {
                v = *(const bf16x8*)&qdw_b[((size_t)((b * 64 + h) * 64 + w)) * 768 + 64 + (k0 - 576) + kc];
            }
            *(bf16x8*)&As[r][kc] = v;
        }
        for (int idx = tid; idx < 640; idx += 256) {
            int r = idx >> 2, kc = (idx & 3) * 8;
            *(bf16x8*)&Bs[r][kc] = *(const bf16x8*)&cwT_b[r * 768 + k0 + kc];
        }
        __syncthreads();
        bf16x8 afr = *(const bf16x8*)&As[wr * 16 + l15][lhi * 8];
        #pragma unroll
        for (int j = 0; j < 5; j++) {
            bf16x8 bfr = *(const bf16x8*)&Bs[wc * 80 + j * 16 + l15][lhi * 8];
            acc[j] = __builtin_amdgcn_mfma_f32_16x16x32_bf16(afr, bfr, acc[j], 0, 0, 0);
        }
        __syncthreads();
    }
    int row = p0 + wr * 16 + lhi * 4;
    #pragma unroll
    for (int j = 0; j < 5; j++) {
        int col = wc * 80 + j * 16 + l15;
        float bv = cb[col];
        #pragma unroll
        for (int r = 0; r < 4; r++)
            offmask[(size_t)(row + r) * 160 + col] = acc[j][r] + bv;
    }
}

// ---- deformable gather + softmax + weighted V sum (bf16 maps) ----
__global__ __launch_bounds__(256) void deform_attn(const u16* __restrict__ qdw_b,
        const float* __restrict__ offmask, u16* __restrict__ attn_b) {
    int tid = threadIdx.x;
    int unit = blockIdx.x * 8 + (tid >> 5);
    int lane = tid & 31;
    int b = unit / (8 * PP);
    int rem = unit % (8 * PP);
    int g = rem / PP;
    int p = rem % PP;
    int w = p & 63, h = p >> 6;
    const float scale = 0.17677669529663687f;  // 32^-0.5
    float qv = b2f(qdw_b[((size_t)((b * 64 + h) * 64 + w)) * 768 + g * 32 + lane]) * scale;
    const float* om = offmask + (size_t)(b * PP + p) * 160;
    float logit[KPT], vs[KPT];
    #pragma unroll
    for (int k_ = 0; k_ < KPT; k_++) {
        float dx = om[g * 18 + 2 * k_];
        float dy = om[g * 18 + 2 * k_ + 1];
        float cx = fminf(fmaxf((float)w + dx, 0.f), 63.f);
        float cy = fminf(fmaxf((float)h + dy, 0.f), 63.f);
        float x0f = floorf(cx), y0f = floorf(cy);
        float wx = cx - x0f, wy = cy - y0f;
        int x0 = (int)x0f, y0 = (int)y0f;
        int x1 = min(x0 + 1, 63), y1 = min(y0 + 1, 63);
        int ch_k = 256 + g * 32 + lane;
        int ch_v = 512 + g * 32 + lane;
        size_t b00 = ((size_t)((b * 64 + y0) * 64 + x0)) * 768;
        size_t b01 = ((size_t)((b * 64 + y0) * 64 + x1)) * 768;
        size_t b10 = ((size_t)((b * 64 + y1) * 64 + x0)) * 768;
        size_t b11 = ((size_t)((b * 64 + y1) * 64 + x1)) * 768;
        float w00 = (1.f - wx) * (1.f - wy), w01 = wx * (1.f - wy);
        float w10 = (1.f - wx) * wy,         w11 = wx * wy;
        float kk = b2f(qdw_b[b00 + ch_k]) * w00 + b2f(qdw_b[b01 + ch_k]) * w01
                 + b2f(qdw_b[b10 + ch_k]) * w10 + b2f(qdw_b[b11 + ch_k]) * w11;
        float vv = b2f(qdw_b[b00 + ch_v]) * w00 + b2f(qdw_b[b01 + ch_v]) * w01
                 + b2f(qdw_b[b10 + ch_v]) * w10 + b2f(qdw_b[b11 + ch_v]) * w11;
        float m = om[144 + k_];
        float part = qv * kk;
        part += __shfl_xor(part, 16);
        part += __shfl_xor(part, 8);
        part += __shfl_xor(part, 4);
        part += __shfl_xor(part, 2);
        part += __shfl_xor(part, 1);
        logit[k_] = part * m;
        vs[k_] = vv * m;
    }
    float mx = logit[0];
    #pragma unroll
    for (int k_ = 1; k_ < KPT; k_++) mx = fmaxf(mx, logit[k_]);
    float s = 0.f, e[KPT];
    #pragma unroll
    for (int k_ = 0; k_ < KPT; k_++) { e[k_] = expf(logit[k_] - mx); s += e[k_]; }
    float inv = 1.f / s;
    float outv = 0.f;
    #pragma unroll
    for (int k_ = 0; k_ < KPT; k_++) outv += e[k_] * vs[k_];
    attn_b[(size_t)(b * PP + p) * 256 + g * 32 + lane] = f2b(outv * inv);
}

extern "C" void kernel_launch(void* const* d_in, const int* in_sizes, int n_in,
                              void* d_out, int out_size, void* d_ws, size_t ws_size,
                              hipStream_t stream) {
    const float* x            = (const float*)d_in[0];
    const float* qkv_w        = (const float*)d_in[1];
    const float* qkv_b        = (const float*)d_in[2];
    const float* dw_w         = (const float*)d_in[3];
    const float* dw_b         = (const float*)d_in[4];
    const float* off_pconv_w  = (const float*)d_in[5];
    const float* off_w        = (const float*)d_in[6];
    const float* off_b        = (const float*)d_in[7];
    const float* mask_pconv_w = (const float*)d_in[8];
    const float* mask_w       = (const float*)d_in[9];
    const float* mask_b       = (const float*)d_in[10];
    const float* proj_w       = (const float*)d_in[11];
    const float* proj_b       = (const float*)d_in[12];

    char* ws = (char*)d_ws;
    u16*   x_b        = (u16*)(ws);                       size_t off = 8192ull*256*2;
    u16*   qkv_wT_b   = (u16*)(ws + off);                 off += 768ull*256*2;
    u16*   proj_wT_b  = (u16*)(ws + off);                 off += 256ull*256*2;
    u16*   qkv_bf     = (u16*)(ws + off);                 off += 8192ull*768*2;
    u16*   qdw_b      = (u16*)(ws + off);                 off += 8192ull*768*2;
    u16*   cwT_b      = (u16*)(ws + off);                 off += 160ull*768*2;
    float* cb         = (float*)(ws + off);               off += 256*4;
    float* offmask    = (float*)(ws + off);               off += 8192ull*160*4;
    u16*   attn_b     = (u16*)(ws + off);                 off += 8192ull*256*2;

    // 1) convert inputs to bf16 (weights transposed)
    convert_inputs<<<9216, 256, 0, stream>>>(x, qkv_w, proj_w, x_b, qkv_wT_b, proj_wT_b);
    // 2) composite offset/mask weights (independent)
    make_cw<<<768, 160, 0, stream>>>(off_pconv_w, off_w, off_b,
                                     mask_pconv_w, mask_w, mask_b, cwT_b, cb);
    // 3) qkv = x @ qkv_w + b   (bf16 MFMA, bf16 out)
    mfma_gemm<true><<<dim3(64, 12), 256, 0, stream>>>(x_b, qkv_wT_b, qkv_b,
                                                      qkv_bf, 8192, 768, 256);
    // 4) depthwise 3x3
    dwconv_b<<<3072, 256, 0, stream>>>(qkv_bf, dw_w, dw_b, qdw_b);
    // 5) offsets + mask (im2col MFMA)
    offmask_mfma<<<256, 256, 0, stream>>>(qdw_b, cwT_b, cb, offmask);
    // 6) deformable attention
    deform_attn<<<8192, 256, 0, stream>>>(qdw_b, offmask, attn_b);
    // 7) projection (fp32 out)
    mfma_gemm<false><<<dim3(64, 4), 256, 0, stream>>>(attn_b, proj_wT_b, proj_b,
                                                      d_out, 8192, 256, 256);
}

// Round 9
// 193.744 us; speedup vs baseline: 1.7450x; 1.0270x over previous
//
#include <hip/hip_runtime.h>

typedef unsigned short u16;
typedef unsigned int u32;
typedef short bf16x8 __attribute__((ext_vector_type(8)));  // 8 bf16 (4 VGPRs)
typedef float f32x4 __attribute__((ext_vector_type(4)));

#define PP 4096
#define KPT 9

__device__ __forceinline__ u16 f2b(float f) {
    union { float f; unsigned int u; } v; v.f = f;
    unsigned int u = v.u;
    unsigned int r = u + 0x7FFFu + ((u >> 16) & 1u);   // RNE
    return (u16)(r >> 16);
}
__device__ __forceinline__ float b2f(u16 b) {
    union { unsigned int u; float f; } v; v.u = ((unsigned int)b) << 16;
    return v.f;
}

// ---- convert x (copy), qkv_w & proj_w (transpose) to bf16 ----
__global__ __launch_bounds__(256) void convert_inputs(
        const float* __restrict__ x, const float* __restrict__ qkv_w,
        const float* __restrict__ proj_w,
        u16* __restrict__ x_b, u16* __restrict__ qkv_wT_b, u16* __restrict__ proj_wT_b) {
    int idx = blockIdx.x * 256 + threadIdx.x;
    if (idx < 2097152) { x_b[idx] = f2b(x[idx]); return; }
    int i2 = idx - 2097152;
    if (i2 < 196608) {                       // qkv_w [256][768] -> T [768][256]
        int r = i2 / 768, c = i2 % 768;
        qkv_wT_b[c * 256 + r] = f2b(qkv_w[i2]);
        return;
    }
    int i3 = i2 - 196608;                    // proj_w [256][256] -> T
    int r = i3 >> 8, c = i3 & 255;
    proj_wT_b[c * 256 + r] = f2b(proj_w[i3]);
}

// ---- generic MFMA GEMM: out = A[M][K] * BT[N][K]^T + bias ----
// BM=128, BN=64, BK=32, 256 threads (4 waves, 2x2), wave tile 64x32
template<bool OUT_BF16>
__global__ __launch_bounds__(256) void mfma_gemm(
        const u16* __restrict__ A, const u16* __restrict__ BT,
        const float* __restrict__ bias, void* __restrict__ out,
        int M, int N, int K) {
    __shared__ u16 As[128][40];
    __shared__ u16 Bs[64][40];
    int tid = threadIdx.x;
    int row0 = blockIdx.x * 128, col0 = blockIdx.y * 64;
    int wid = tid >> 6, lane = tid & 63;
    int wr = wid >> 1, wc = wid & 1;
    int l15 = lane & 15, lhi = lane >> 4;
    f32x4 acc[4][2] = {};
    for (int k0 = 0; k0 < K; k0 += 32) {
        #pragma unroll
        for (int q = 0; q < 2; q++) {
            int idx = tid + q * 256;
            int r = idx >> 2, kc = (idx & 3) * 8;
            *(bf16x8*)&As[r][kc] = *(const bf16x8*)&A[(size_t)(row0 + r) * K + k0 + kc];
        }
        {
            int r = tid >> 2, kc = (tid & 3) * 8;
            *(bf16x8*)&Bs[r][kc] = *(const bf16x8*)&BT[(size_t)(col0 + r) * K + k0 + kc];
        }
        __syncthreads();
        bf16x8 bfr[2];
        #pragma unroll
        for (int j = 0; j < 2; j++)
            bfr[j] = *(const bf16x8*)&Bs[wc * 32 + j * 16 + l15][lhi * 8];
        #pragma unroll
        for (int i = 0; i < 4; i++) {
            bf16x8 afr = *(const bf16x8*)&As[wr * 64 + i * 16 + l15][lhi * 8];
            #pragma unroll
            for (int j = 0; j < 2; j++)
                acc[i][j] = __builtin_amdgcn_mfma_f32_16x16x32_bf16(afr, bfr[j], acc[i][j], 0, 0, 0);
        }
        __syncthreads();
    }
    #pragma unroll
    for (int i = 0; i < 4; i++) {
        int row = row0 + wr * 64 + i * 16 + lhi * 4;
        #pragma unroll
        for (int j = 0; j < 2; j++) {
            int col = col0 + wc * 32 + j * 16 + l15;
            float bv = bias[col];
            #pragma unroll
            for (int r = 0; r < 4; r++) {
                float v = acc[i][j][r] + bv;
                if (OUT_BF16) ((u16*)out)[(size_t)(row + r) * N + col] = f2b(v);
                else          ((float*)out)[(size_t)(row + r) * N + col] = v;
            }
        }
    }
}

// ---- depthwise 3x3 (SAME), bf16 in/out, fp32 accum, 8 ch/thread ----
__global__ __launch_bounds__(256) void dwconv_b(const u16* __restrict__ qkv_b,
        const float* __restrict__ dww, const float* __restrict__ dwb,
        u16* __restrict__ out) {
    int idx = blockIdx.x * 256 + threadIdx.x;       // 8192*96
    int c8 = (idx % 96) * 8;
    int pix = idx / 96;
    int w = pix & 63, h = (pix >> 6) & 63, b = pix >> 12;
    float acc[8];
    #pragma unroll
    for (int j = 0; j < 8; j++) acc[j] = dwb[c8 + j];
    #pragma unroll
    for (int ky = 0; ky < 3; ky++) {
        int hh = h + ky - 1;
        if (hh < 0 || hh >= 64) continue;
        #pragma unroll
        for (int kx = 0; kx < 3; kx++) {
            int ww = w + kx - 1;
            if (ww < 0 || ww >= 64) continue;
            bf16x8 v = *(const bf16x8*)&qkv_b[((size_t)((b * 64 + hh) * 64 + ww)) * 768 + c8];
            #pragma unroll
            for (int j = 0; j < 8; j++)
                acc[j] += b2f((u16)v[j]) * dww[(ky * 3 + kx) * 768 + c8 + j];
        }
    }
    bf16x8 o;
    #pragma unroll
    for (int j = 0; j < 8; j++) o[j] = (short)f2b(acc[j]);
    *(bf16x8*)&out[(size_t)idx * 8] = o;
}

// ---- composite offset/mask weights (fold pconv + linear), bf16 transposed ----
// cwT_b layout: [160][768]  (o-major). o: 0..143 offsets, 144..152 mask, rest 0.
__global__ void make_cw(const float* __restrict__ off_pconv_w,
        const float* __restrict__ off_w, const float* __restrict__ off_b,
        const float* __restrict__ mask_pconv_w, const float* __restrict__ mask_w,
        const float* __restrict__ mask_b, u16* __restrict__ cwT_b,
        float* __restrict__ cb) {
    int k = blockIdx.x;      // 0..767
    int o = threadIdx.x;     // 0..159
    float val = 0.f;
    if (o < 153) {
        if (k < 576) {
            int patch = k >> 6, i = k & 63;
            if (o < 144) {
                int g = o / 18, oo = o % 18;
                for (int c = 0; c < 64; c++)
                    val += off_w[(g * 18 + oo) * 256 + c] *
                           off_pconv_w[((g * 64 + c) * 64 + i) * 9 + patch];
            } else {
                int oo = o - 144;
                for (int c = 0; c < 64; c++)
                    val += mask_w[oo * 256 + c] * mask_pconv_w[(c * 64 + i) * 9 + patch];
            }
        } else {
            int j = k - 576;
            if (o < 144) {
                int g = o / 18, oo = o % 18;
                val = off_w[(g * 18 + oo) * 256 + 64 + j];
            } else {
                val = mask_w[(o - 144) * 256 + 64 + j];
            }
        }
    }
    cwT_b[o * 768 + k] = f2b(val);
    if (k == 0) {
        float bv = 0.f;
        if (o < 144) {
            int g = o / 18, oo = o % 18;
            const float PTSf[18] = {-1,-1,-1,0,-1,1,0,-1,0,0,0,1,1,-1,1,0,1,1};
            bv = off_b[g * 18 + oo] + PTSf[oo] * (float)(2 * g + 1);
        } else if (o < 153) {
            bv = mask_b[o - 144];
        }
        cb[o] = bv;
    }
}

// ---- offsets+mask via im2col MFMA GEMM: M=8192(32/blk) K=768 N=160 ----
__global__ __launch_bounds__(256) void offmask_mfma(const u16* __restrict__ qdw_b,
        const u16* __restrict__ cwT_b, const float* __restrict__ cb,
        float* __restrict__ offmask) {
    __shared__ u16 As[32][40];
    __shared__ u16 Bs[160][40];
    int tid = threadIdx.x;
    int p0 = blockIdx.x * 32;
    int wid = tid >> 6, lane = tid & 63;
    int wr = wid >> 1, wc = wid & 1;
    int l15 = lane & 15, lhi = lane >> 4;
    f32x4 acc[5] = {};
    for (int k0 = 0; k0 < 768; k0 += 32) {
        if (tid < 128) {
            int r = tid >> 2, kc = (tid & 3) * 8;
            int pixel = p0 + r;
            int w = pixel & 63, h = (pixel >> 6) & 63, b = pixel >> 12;
            bf16x8 v = {};
            if (k0 < 576) {
                int patch = k0 >> 6;
                int dy = patch / 3 - 1, dx = patch % 3 - 1;
                int hh = h + dy, ww = w + dx;
                if (hh >= 0 && hh < 64 && ww >= 0 && ww < 64)
                    v = *(const bf16x8*)&qdw_b[((size_t)((b * 64 + hh) * 64 + ww)) * 768 + (k0 & 63) + kc];
            } else {
                v = *(const bf16x8*)&qdw_b[((size_t)((b * 64 + h) * 64 + w)) * 768 + 64 + (k0 - 576) + kc];
            }
            *(bf16x8*)&As[r][kc] = v;
        }
        for (int idx = tid; idx < 640; idx += 256) {
            int r = idx >> 2, kc = (idx & 3) * 8;
            *(bf16x8*)&Bs[r][kc] = *(const bf16x8*)&cwT_b[r * 768 + k0 + kc];
        }
        __syncthreads();
        bf16x8 afr = *(const bf16x8*)&As[wr * 16 + l15][lhi * 8];
        #pragma unroll
        for (int j = 0; j < 5; j++) {
            bf16x8 bfr = *(const bf16x8*)&Bs[wc * 80 + j * 16 + l15][lhi * 8];
            acc[j] = __builtin_amdgcn_mfma_f32_16x16x32_bf16(afr, bfr, acc[j], 0, 0, 0);
        }
        __syncthreads();
    }
    int row = p0 + wr * 16 + lhi * 4;
    #pragma unroll
    for (int j = 0; j < 5; j++) {
        int col = wc * 80 + j * 16 + l15;
        float bv = cb[col];
        #pragma unroll
        for (int r = 0; r < 4; r++)
            offmask[(size_t)(row + r) * 160 + col] = acc[j][r] + bv;
    }
}

// ---- precompute per-(pix,g,k) sample params: packed corner idx + wx,wy,mask ----
// pre[pix*72 + g*9 + k] = {u32(idx00 | dxo<<16 | dyo<<17), wx, wy, mask}
__global__ __launch_bounds__(256) void precompute_pts(const float* __restrict__ offmask,
        float4* __restrict__ pre) {
    int idx = blockIdx.x * 256 + threadIdx.x;      // 2*4096*72 = 589824 items
    if (idx >= 2 * PP * 72) return;
    int item = idx % 72;
    int pix = idx / 72;                            // b*4096 + p
    int g = item / 9, k = item % 9;
    int w = pix & 63, h = (pix >> 6) & 63;
    const float* om = offmask + (size_t)pix * 160;
    float dx = om[g * 18 + 2 * k];
    float dy = om[g * 18 + 2 * k + 1];
    float m  = om[144 + k];
    float cx = fminf(fmaxf((float)w + dx, 0.f), 63.f);
    float cy = fminf(fmaxf((float)h + dy, 0.f), 63.f);
    float x0f = floorf(cx), y0f = floorf(cy);
    int x0 = (int)x0f, y0 = (int)y0f;
    u32 idx00 = (u32)((pix & ~4095) | (y0 << 6) | x0);   // corner pixel index
    u32 pk = idx00 | ((x0 < 63) ? 0x10000u : 0u) | ((y0 < 63) ? 0x20000u : 0u);
    float4 o;
    o.x = __uint_as_float(pk);
    o.y = cx - x0f;
    o.z = cy - y0f;
    o.w = m;
    pre[idx] = o;
}

// ---- deformable gather + softmax + weighted V sum ----
// 16 lanes per (b,g,p) unit, 2 channels/lane via u32 bf16-pair loads.
__global__ __launch_bounds__(256) void deform_attn(const u16* __restrict__ qdw_b,
        const float4* __restrict__ pre, u16* __restrict__ attn_b) {
    int tid = threadIdx.x;
    int unit = blockIdx.x * 16 + (tid >> 4);   // 65536 units
    int cl = tid & 15;                         // channel-pair lane
    int b = unit >> 15;
    int g = (unit >> 12) & 7;
    int p = unit & 4095;
    int pix = (b << 12) | p;
    const float scale = 0.17677669529663687f;  // 32^-0.5
    u32 qu = *(const u32*)&qdw_b[(size_t)pix * 768 + g * 32 + 2 * cl];
    float qlo = __uint_as_float(qu << 16) * scale;
    float qhi = __uint_as_float(qu & 0xFFFF0000u) * scale;
    const float4* pp = pre + (size_t)pix * 72 + g * 9;
    const char* base = (const char*)qdw_b;
    // byte offset of this lane's k-channel pair within a pixel row (row = 1536 B)
    u32 ckb = (u32)(512 + (g * 32 + 2 * cl) * 2);
    float logit[KPT], vlo[KPT], vhi[KPT];
    #pragma unroll
    for (int k_ = 0; k_ < KPT; k_++) {
        float4 q4 = pp[k_];                       // uniform across the 16-lane group
        u32 pk = __float_as_uint(q4.x);
        float wx = q4.y, wy = q4.z, m = q4.w;
        u32 o00 = (pk & 0xFFFFu) * 1536u + ckb;
        u32 dX = (pk & 0x10000u) ? 1536u : 0u;
        u32 dY = (pk & 0x20000u) ? 98304u : 0u;
        u32 o01 = o00 + dX, o10 = o00 + dY, o11 = o00 + dY + dX;
        u32 k00 = *(const u32*)(base + o00);
        u32 v00 = *(const u32*)(base + o00 + 512);
        u32 k01 = *(const u32*)(base + o01);
        u32 v01 = *(const u32*)(base + o01 + 512);
        u32 k10 = *(const u32*)(base + o10);
        u32 v10 = *(const u32*)(base + o10 + 512);
        u32 k11 = *(const u32*)(base + o11);
        u32 v11 = *(const u32*)(base + o11 + 512);
        float w00 = (1.f - wx) * (1.f - wy), w01 = wx * (1.f - wy);
        float w10 = (1.f - wx) * wy,         w11 = wx * wy;
        float klo = __uint_as_float(k00 << 16) * w00 + __uint_as_float(k01 << 16) * w01
                  + __uint_as_float(k10 << 16) * w10 + __uint_as_float(k11 << 16) * w11;
        float khi = __uint_as_float(k00 & 0xFFFF0000u) * w00 + __uint_as_float(k01 & 0xFFFF0000u) * w01
                  + __uint_as_float(k10 & 0xFFFF0000u) * w10 + __uint_as_float(k11 & 0xFFFF0000u) * w11;
        float Vlo = __uint_as_float(v00 << 16) * w00 + __uint_as_float(v01 << 16) * w01
                  + __uint_as_float(v10 << 16) * w10 + __uint_as_float(v11 << 16) * w11;
        float Vhi = __uint_as_float(v00 & 0xFFFF0000u) * w00 + __uint_as_float(v01 & 0xFFFF0000u) * w01
                  + __uint_as_float(v10 & 0xFFFF0000u) * w10 + __uint_as_float(v11 & 0xFFFF0000u) * w11;
        float part = qlo * klo + qhi * khi;
        part += __shfl_xor(part, 8);
        part += __shfl_xor(part, 4);
        part += __shfl_xor(part, 2);
        part += __shfl_xor(part, 1);
        logit[k_] = part * m;
        vlo[k_] = Vlo * m;
        vhi[k_] = Vhi * m;
    }
    float mx = logit[0];
    #pragma unroll
    for (int k_ = 1; k_ < KPT; k_++) mx = fmaxf(mx, logit[k_]);
    float s = 0.f;
    #pragma unroll
    for (int k_ = 0; k_ < KPT; k_++) { logit[k_] = expf(logit[k_] - mx); s += logit[k_]; }
    float inv = 1.f / s;
    float olo = 0.f, ohi = 0.f;
    #pragma unroll
    for (int k_ = 0; k_ < KPT; k_++) { olo += logit[k_] * vlo[k_]; ohi += logit[k_] * vhi[k_]; }
    olo *= inv; ohi *= inv;
    u32 outw = (u32)f2b(olo) | ((u32)f2b(ohi) << 16);
    *(u32*)&attn_b[(size_t)pix * 256 + g * 32 + 2 * cl] = outw;
}

extern "C" void kernel_launch(void* const* d_in, const int* in_sizes, int n_in,
                              void* d_out, int out_size, void* d_ws, size_t ws_size,
                              hipStream_t stream) {
    const float* x            = (const float*)d_in[0];
    const float* qkv_w        = (const float*)d_in[1];
    const float* qkv_b        = (const float*)d_in[2];
    const float* dw_w         = (const float*)d_in[3];
    const float* dw_b         = (const float*)d_in[4];
    const float* off_pconv_w  = (const float*)d_in[5];
    const float* off_w        = (const float*)d_in[6];
    const float* off_b        = (const float*)d_in[7];
    const float* mask_pconv_w = (const float*)d_in[8];
    const float* mask_w       = (const float*)d_in[9];
    const float* mask_b       = (const float*)d_in[10];
    const float* proj_w       = (const float*)d_in[11];
    const float* proj_b       = (const float*)d_in[12];

    char* ws = (char*)d_ws;
    u16*   x_b        = (u16*)(ws);                       size_t off = 8192ull*256*2;
    u16*   qkv_wT_b   = (u16*)(ws + off);                 off += 768ull*256*2;
    u16*   proj_wT_b  = (u16*)(ws + off);                 off += 256ull*256*2;
    u16*   qkv_bf     = (u16*)(ws + off);                 off += 8192ull*768*2;
    u16*   qdw_b      = (u16*)(ws + off);                 off += 8192ull*768*2;
    u16*   cwT_b      = (u16*)(ws + off);                 off += 160ull*768*2;
    float* cb         = (float*)(ws + off);               off += 256*4;
    float* offmask    = (float*)(ws + off);               off += 8192ull*160*4;
    u16*   attn_b     = (u16*)(ws + off);                 off += 8192ull*256*2;
    float4* pre       = (float4*)(ws + off);              off += 589824ull*16;

    // 1) convert inputs to bf16 (weights transposed)
    convert_inputs<<<9216, 256, 0, stream>>>(x, qkv_w, proj_w, x_b, qkv_wT_b, proj_wT_b);
    // 2) composite offset/mask weights (independent)
    make_cw<<<768, 160, 0, stream>>>(off_pconv_w, off_w, off_b,
                                     mask_pconv_w, mask_w, mask_b, cwT_b, cb);
    // 3) qkv = x @ qkv_w + b   (bf16 MFMA, bf16 out)
    mfma_gemm<true><<<dim3(64, 12), 256, 0, stream>>>(x_b, qkv_wT_b, qkv_b,
                                                      qkv_bf, 8192, 768, 256);
    // 4) depthwise 3x3
    dwconv_b<<<3072, 256, 0, stream>>>(qkv_bf, dw_w, dw_b, qdw_b);
    // 5) offsets + mask (im2col MFMA)
    offmask_mfma<<<256, 256, 0, stream>>>(qdw_b, cwT_b, cb, offmask);
    // 6) precompute sample points (uniform work hoisted out of deform_attn)
    precompute_pts<<<2304, 256, 0, stream>>>(offmask, pre);
    // 7) deformable attention (16 lanes/unit, u32 channel-pair loads)
    deform_attn<<<4096, 256, 0, stream>>>(qdw_b, pre, attn_b);
    // 8) projection (fp32 out)
    mfma_gemm<false><<<dim3(64, 4), 256, 0, stream>>>(attn_b, proj_wT_b, proj_b,
                                                      d_out, 8192, 256, 256);
}

// Round 10
// 173.225 us; speedup vs baseline: 1.9517x; 1.1185x over previous
//
#include <hip/hip_runtime.h>

typedef unsigned short u16;
typedef unsigned int u32;
typedef short bf16x8 __attribute__((ext_vector_type(8)));  // 8 bf16 (4 VGPRs)
typedef float f32x4 __attribute__((ext_vector_type(4)));
typedef float f32x2 __attribute__((ext_vector_type(2)));

#define PP 4096
#define KPT 9

__device__ __forceinline__ u16 f2b(float f) {
    union { float f; unsigned int u; } v; v.f = f;
    unsigned int u = v.u;
    unsigned int r = u + 0x7FFFu + ((u >> 16) & 1u);   // RNE
    return (u16)(r >> 16);
}
__device__ __forceinline__ float b2f(u16 b) {
    union { unsigned int u; float f; } v; v.u = ((unsigned int)b) << 16;
    return v.f;
}
__device__ __forceinline__ f32x2 unpk2(u32 u) {
    f32x2 r;
    r.x = __uint_as_float(u << 16);
    r.y = __uint_as_float(u & 0xFFFF0000u);
    return r;
}

// ---- convert qkv_w & proj_w (transpose) to bf16 ----
__global__ __launch_bounds__(256) void convert_inputs(
        const float* __restrict__ qkv_w, const float* __restrict__ proj_w,
        u16* __restrict__ qkv_wT_b, u16* __restrict__ proj_wT_b) {
    int idx = blockIdx.x * 256 + threadIdx.x;     // 262144 total
    if (idx < 196608) {                           // qkv_w [256][768] -> T [768][256]
        int r = idx / 768, c = idx % 768;
        qkv_wT_b[c * 256 + r] = f2b(qkv_w[idx]);
        return;
    }
    int i3 = idx - 196608;                        // proj_w [256][256] -> T
    int r = i3 >> 8, c = i3 & 255;
    proj_wT_b[c * 256 + r] = f2b(proj_w[i3]);
}

// ---- generic MFMA GEMM: out = A[M][K] * BT[N][K]^T + bias ----
// BM=128, BN=64, BK=32, 256 threads (4 waves, 2x2), wave tile 64x32
// A_F32: A is fp32, converted to bf16 during staging.
template<bool OUT_BF16, bool A_F32>
__global__ __launch_bounds__(256) void mfma_gemm(
        const void* __restrict__ Av, const u16* __restrict__ BT,
        const float* __restrict__ bias, void* __restrict__ out,
        int M, int N, int K) {
    __shared__ u16 As[128][40];
    __shared__ u16 Bs[64][40];
    int tid = threadIdx.x;
    int row0 = blockIdx.x * 128, col0 = blockIdx.y * 64;
    int wid = tid >> 6, lane = tid & 63;
    int wr = wid >> 1, wc = wid & 1;
    int l15 = lane & 15, lhi = lane >> 4;
    f32x4 acc[4][2] = {};
    for (int k0 = 0; k0 < K; k0 += 32) {
        #pragma unroll
        for (int q = 0; q < 2; q++) {
            int idx = tid + q * 256;
            int r = idx >> 2, kc = (idx & 3) * 8;
            if (A_F32) {
                const float* Af = (const float*)Av;
                f32x4 a0 = *(const f32x4*)&Af[(size_t)(row0 + r) * K + k0 + kc];
                f32x4 a1 = *(const f32x4*)&Af[(size_t)(row0 + r) * K + k0 + kc + 4];
                bf16x8 v;
                #pragma unroll
                for (int j = 0; j < 4; j++) { v[j] = (short)f2b(a0[j]); v[4+j] = (short)f2b(a1[j]); }
                *(bf16x8*)&As[r][kc] = v;
            } else {
                const u16* Ab = (const u16*)Av;
                *(bf16x8*)&As[r][kc] = *(const bf16x8*)&Ab[(size_t)(row0 + r) * K + k0 + kc];
            }
        }
        {
            int r = tid >> 2, kc = (tid & 3) * 8;
            *(bf16x8*)&Bs[r][kc] = *(const bf16x8*)&BT[(size_t)(col0 + r) * K + k0 + kc];
        }
        __syncthreads();
        bf16x8 bfr[2];
        #pragma unroll
        for (int j = 0; j < 2; j++)
            bfr[j] = *(const bf16x8*)&Bs[wc * 32 + j * 16 + l15][lhi * 8];
        #pragma unroll
        for (int i = 0; i < 4; i++) {
            bf16x8 afr = *(const bf16x8*)&As[wr * 64 + i * 16 + l15][lhi * 8];
            #pragma unroll
            for (int j = 0; j < 2; j++)
                acc[i][j] = __builtin_amdgcn_mfma_f32_16x16x32_bf16(afr, bfr[j], acc[i][j], 0, 0, 0);
        }
        __syncthreads();
    }
    #pragma unroll
    for (int i = 0; i < 4; i++) {
        int row = row0 + wr * 64 + i * 16 + lhi * 4;
        #pragma unroll
        for (int j = 0; j < 2; j++) {
            int col = col0 + wc * 32 + j * 16 + l15;
            float bv = bias[col];
            #pragma unroll
            for (int r = 0; r < 4; r++) {
                float v = acc[i][j][r] + bv;
                if (OUT_BF16) ((u16*)out)[(size_t)(row + r) * N + col] = f2b(v);
                else          ((float*)out)[(size_t)(row + r) * N + col] = v;
            }
        }
    }
}

// ---- depthwise 3x3 (SAME), bf16 in/out, fp32 accum, 8 ch/thread ----
__global__ __launch_bounds__(256) void dwconv_b(const u16* __restrict__ qkv_b,
        const float* __restrict__ dww, const float* __restrict__ dwb,
        u16* __restrict__ out) {
    int idx = blockIdx.x * 256 + threadIdx.x;       // 8192*96
    int c8 = (idx % 96) * 8;
    int pix = idx / 96;
    int w = pix & 63, h = (pix >> 6) & 63, b = pix >> 12;
    float acc[8];
    #pragma unroll
    for (int j = 0; j < 8; j++) acc[j] = dwb[c8 + j];
    #pragma unroll
    for (int ky = 0; ky < 3; ky++) {
        int hh = h + ky - 1;
        if (hh < 0 || hh >= 64) continue;
        #pragma unroll
        for (int kx = 0; kx < 3; kx++) {
            int ww = w + kx - 1;
            if (ww < 0 || ww >= 64) continue;
            bf16x8 v = *(const bf16x8*)&qkv_b[((size_t)((b * 64 + hh) * 64 + ww)) * 768 + c8];
            #pragma unroll
            for (int j = 0; j < 8; j++)
                acc[j] += b2f((u16)v[j]) * dww[(ky * 3 + kx) * 768 + c8 + j];
        }
    }
    bf16x8 o;
    #pragma unroll
    for (int j = 0; j < 8; j++) o[j] = (short)f2b(acc[j]);
    *(bf16x8*)&out[(size_t)idx * 8] = o;
}

// ---- composite offset/mask weights (fold pconv + linear), bf16 transposed ----
// cwT_b layout: [160][768]  (o-major). o: 0..143 offsets, 144..152 mask, rest 0.
__global__ void make_cw(const float* __restrict__ off_pconv_w,
        const float* __restrict__ off_w, const float* __restrict__ off_b,
        const float* __restrict__ mask_pconv_w, const float* __restrict__ mask_w,
        const float* __restrict__ mask_b, u16* __restrict__ cwT_b,
        float* __restrict__ cb) {
    int k = blockIdx.x;      // 0..767
    int o = threadIdx.x;     // 0..159
    float val = 0.f;
    if (o < 153) {
        if (k < 576) {
            int patch = k >> 6, i = k & 63;
            if (o < 144) {
                int g = o / 18, oo = o % 18;
                for (int c = 0; c < 64; c++)
                    val += off_w[(g * 18 + oo) * 256 + c] *
                           off_pconv_w[((g * 64 + c) * 64 + i) * 9 + patch];
            } else {
                int oo = o - 144;
                for (int c = 0; c < 64; c++)
                    val += mask_w[oo * 256 + c] * mask_pconv_w[(c * 64 + i) * 9 + patch];
            }
        } else {
            int j = k - 576;
            if (o < 144) {
                int g = o / 18, oo = o % 18;
                val = off_w[(g * 18 + oo) * 256 + 64 + j];
            } else {
                val = mask_w[(o - 144) * 256 + 64 + j];
            }
        }
    }
    cwT_b[o * 768 + k] = f2b(val);
    if (k == 0) {
        float bv = 0.f;
        if (o < 144) {
            int g = o / 18, oo = o % 18;
            const float PTSf[18] = {-1,-1,-1,0,-1,1,0,-1,0,0,0,1,1,-1,1,0,1,1};
            bv = off_b[g * 18 + oo] + PTSf[oo] * (float)(2 * g + 1);
        } else if (o < 153) {
            bv = mask_b[o - 144];
        }
        cb[o] = bv;
    }
}

// ---- offsets+mask via im2col MFMA GEMM, K-split x2 for occupancy ----
// grid 512: blockIdx&1 = K-half (0: k[0,384)+bias -> om0, 1: k[384,768) -> om1)
__global__ __launch_bounds__(256) void offmask_mfma(const u16* __restrict__ qdw_b,
        const u16* __restrict__ cwT_b, const float* __restrict__ cb,
        float* __restrict__ om0, float* __restrict__ om1) {
    __shared__ u16 As[32][40];
    __shared__ u16 Bs[160][40];
    int tid = threadIdx.x;
    int half = blockIdx.x & 1;
    int p0 = (blockIdx.x >> 1) * 32;
    int kbeg = half ? 384 : 0;
    int kend = kbeg + 384;
    int wid = tid >> 6, lane = tid & 63;
    int wr = wid >> 1, wc = wid & 1;
    int l15 = lane & 15, lhi = lane >> 4;
    f32x4 acc[5] = {};
    for (int k0 = kbeg; k0 < kend; k0 += 32) {
        if (tid < 128) {
            int r = tid >> 2, kc = (tid & 3) * 8;
            int pixel = p0 + r;
            int w = pixel & 63, h = (pixel >> 6) & 63, b = pixel >> 12;
            bf16x8 v = {};
            if (k0 < 576) {
                int patch = k0 >> 6;
                int dy = patch / 3 - 1, dx = patch % 3 - 1;
                int hh = h + dy, ww = w + dx;
                if (hh >= 0 && hh < 64 && ww >= 0 && ww < 64)
                    v = *(const bf16x8*)&qdw_b[((size_t)((b * 64 + hh) * 64 + ww)) * 768 + (k0 & 63) + kc];
            } else {
                v = *(const bf16x8*)&qdw_b[((size_t)((b * 64 + h) * 64 + w)) * 768 + 64 + (k0 - 576) + kc];
            }
            *(bf16x8*)&As[r][kc] = v;
        }
        for (int idx = tid; idx < 640; idx += 256) {
            int r = idx >> 2, kc = (idx & 3) * 8;
            *(bf16x8*)&Bs[r][kc] = *(const bf16x8*)&cwT_b[r * 768 + k0 + kc];
        }
        __syncthreads();
        bf16x8 afr = *(const bf16x8*)&As[wr * 16 + l15][lhi * 8];
        #pragma unroll
        for (int j = 0; j < 5; j++) {
            bf16x8 bfr = *(const bf16x8*)&Bs[wc * 80 + j * 16 + l15][lhi * 8];
            acc[j] = __builtin_amdgcn_mfma_f32_16x16x32_bf16(afr, bfr, acc[j], 0, 0, 0);
        }
        __syncthreads();
    }
    float* dst = half ? om1 : om0;
    int row = p0 + wr * 16 + lhi * 4;
    #pragma unroll
    for (int j = 0; j < 5; j++) {
        int col = wc * 80 + j * 16 + l15;
        float bv = half ? 0.f : cb[col];
        #pragma unroll
        for (int r = 0; r < 4; r++)
            dst[(size_t)(row + r) * 160 + col] = acc[j][r] + bv;
    }
}

// ---- precompute per-(pix,g,k) sample params: packed corner idx + wx,wy,mask ----
// pre[pix*72 + g*9 + k] = {u32(idx00 | dxo<<16 | dyo<<17), wx, wy, mask}
__global__ __launch_bounds__(256) void precompute_pts(const float* __restrict__ om0,
        const float* __restrict__ om1, float4* __restrict__ pre) {
    int idx = blockIdx.x * 256 + threadIdx.x;      // 2*4096*72 = 589824 items
    if (idx >= 2 * PP * 72) return;
    int item = idx % 72;
    int pix = idx / 72;                            // b*4096 + p
    int g = item / 9, k = item % 9;
    int w = pix & 63, h = (pix >> 6) & 63;
    size_t rowb = (size_t)pix * 160;
    float dx = om0[rowb + g * 18 + 2 * k]     + om1[rowb + g * 18 + 2 * k];
    float dy = om0[rowb + g * 18 + 2 * k + 1] + om1[rowb + g * 18 + 2 * k + 1];
    float m  = om0[rowb + 144 + k]            + om1[rowb + 144 + k];
    float cx = fminf(fmaxf((float)w + dx, 0.f), 63.f);
    float cy = fminf(fmaxf((float)h + dy, 0.f), 63.f);
    float x0f = floorf(cx), y0f = floorf(cy);
    int x0 = (int)x0f, y0 = (int)y0f;
    u32 idx00 = (u32)((pix & ~4095) | (y0 << 6) | x0);   // corner pixel index
    u32 pk = idx00 | ((x0 < 63) ? 0x10000u : 0u) | ((y0 < 63) ? 0x20000u : 0u);
    float4 o;
    o.x = __uint_as_float(pk);
    o.y = cx - x0f;
    o.z = cy - y0f;
    o.w = m;
    pre[idx] = o;
}

// ---- deformable gather + softmax + weighted V sum ----
// 16 lanes per (b,g,p) unit, 2 channels/lane; packed f32x2 math (v_pk_fma_f32).
__global__ __launch_bounds__(256) void deform_attn(const u16* __restrict__ qdw_b,
        const float4* __restrict__ pre, u16* __restrict__ attn_b) {
    int tid = threadIdx.x;
    int unit = blockIdx.x * 16 + (tid >> 4);   // 65536 units
    int cl = tid & 15;                         // channel-pair lane
    int b = unit >> 15;
    int g = (unit >> 12) & 7;
    int p = unit & 4095;
    int pix = (b << 12) | p;
    const float scale = 0.17677669529663687f;  // 32^-0.5
    u32 qu = *(const u32*)&qdw_b[(size_t)pix * 768 + g * 32 + 2 * cl];
    f32x2 q2 = unpk2(qu) * scale;
    const float4* pp = pre + (size_t)pix * 72 + g * 9;
    const char* base = (const char*)qdw_b;
    // byte offset of this lane's k-channel pair within a pixel row (row = 1536 B)
    u32 ckb = (u32)(512 + (g * 32 + 2 * cl) * 2);
    float logit[KPT];
    f32x2 vs[KPT];
    #pragma unroll
    for (int k_ = 0; k_ < KPT; k_++) {
        float4 q4 = pp[k_];                       // uniform across the 16-lane group
        u32 pk = __float_as_uint(q4.x);
        float wx = q4.y, wy = q4.z, m = q4.w;
        u32 o00 = (pk & 0xFFFFu) * 1536u + ckb;
        u32 dX = (pk & 0x10000u) ? 1536u : 0u;
        u32 dY = (pk & 0x20000u) ? 98304u : 0u;
        u32 o01 = o00 + dX, o10 = o00 + dY, o11 = o00 + dY + dX;
        u32 k00 = *(const u32*)(base + o00);
        u32 v00 = *(const u32*)(base + o00 + 512);
        u32 k01 = *(const u32*)(base + o01);
        u32 v01 = *(const u32*)(base + o01 + 512);
        u32 k10 = *(const u32*)(base + o10);
        u32 v10 = *(const u32*)(base + o10 + 512);
        u32 k11 = *(const u32*)(base + o11);
        u32 v11 = *(const u32*)(base + o11 + 512);
        float w00 = (1.f - wx) * (1.f - wy), w01 = wx * (1.f - wy);
        float w10 = (1.f - wx) * wy,         w11 = wx * wy;
        f32x2 kk = unpk2(k00) * w00 + unpk2(k01) * w01
                 + unpk2(k10) * w10 + unpk2(k11) * w11;
        f32x2 vv = unpk2(v00) * w00 + unpk2(v01) * w01
                 + unpk2(v10) * w10 + unpk2(v11) * w11;
        f32x2 pr = q2 * kk;
        float part = pr.x + pr.y;
        part += __shfl_xor(part, 8);
        part += __shfl_xor(part, 4);
        part += __shfl_xor(part, 2);
        part += __shfl_xor(part, 1);
        logit[k_] = part * m;
        vs[k_] = vv * m;
    }
    float mx = logit[0];
    #pragma unroll
    for (int k_ = 1; k_ < KPT; k_++) mx = fmaxf(mx, logit[k_]);
    float s = 0.f;
    #pragma unroll
    for (int k_ = 0; k_ < KPT; k_++) { logit[k_] = expf(logit[k_] - mx); s += logit[k_]; }
    float inv = 1.f / s;
    f32x2 o2 = {0.f, 0.f};
    #pragma unroll
    for (int k_ = 0; k_ < KPT; k_++) o2 += vs[k_] * logit[k_];
    o2 *= inv;
    u32 outw = (u32)f2b(o2.x) | ((u32)f2b(o2.y) << 16);
    *(u32*)&attn_b[(size_t)pix * 256 + g * 32 + 2 * cl] = outw;
}

extern "C" void kernel_launch(void* const* d_in, const int* in_sizes, int n_in,
                              void* d_out, int out_size, void* d_ws, size_t ws_size,
                              hipStream_t stream) {
    const float* x            = (const float*)d_in[0];
    const float* qkv_w        = (const float*)d_in[1];
    const float* qkv_b        = (const float*)d_in[2];
    const float* dw_w         = (const float*)d_in[3];
    const float* dw_b         = (const float*)d_in[4];
    const float* off_pconv_w  = (const float*)d_in[5];
    const float* off_w        = (const float*)d_in[6];
    const float* off_b        = (const float*)d_in[7];
    const float* mask_pconv_w = (const float*)d_in[8];
    const float* mask_w       = (const float*)d_in[9];
    const float* mask_b       = (const float*)d_in[10];
    const float* proj_w       = (const float*)d_in[11];
    const float* proj_b       = (const float*)d_in[12];

    char* ws = (char*)d_ws;
    size_t off = 0;
    u16*   qkv_wT_b   = (u16*)(ws + off);                 off += 768ull*256*2;
    u16*   proj_wT_b  = (u16*)(ws + off);                 off += 256ull*256*2;
    u16*   qkv_bf     = (u16*)(ws + off);                 off += 8192ull*768*2;
    u16*   qdw_b      = (u16*)(ws + off);                 off += 8192ull*768*2;
    u16*   cwT_b      = (u16*)(ws + off);                 off += 160ull*768*2;
    float* cb         = (float*)(ws + off);               off += 256*4;
    float* om0        = (float*)(ws + off);               off += 8192ull*160*4;
    float* om1        = (float*)(ws + off);               off += 8192ull*160*4;
    u16*   attn_b     = (u16*)(ws + off);                 off += 8192ull*256*2;
    float4* pre       = (float4*)(ws + off);              off += 589824ull*16;

    // 1) convert weights to bf16 (transposed)
    convert_inputs<<<1024, 256, 0, stream>>>(qkv_w, proj_w, qkv_wT_b, proj_wT_b);
    // 2) composite offset/mask weights (independent)
    make_cw<<<768, 160, 0, stream>>>(off_pconv_w, off_w, off_b,
                                     mask_pconv_w, mask_w, mask_b, cwT_b, cb);
    // 3) qkv = x @ qkv_w + b   (fp32 A converted in staging, bf16 MFMA, bf16 out)
    mfma_gemm<true, true><<<dim3(64, 12), 256, 0, stream>>>(x, qkv_wT_b, qkv_b,
                                                            qkv_bf, 8192, 768, 256);
    // 4) depthwise 3x3
    dwconv_b<<<3072, 256, 0, stream>>>(qkv_bf, dw_w, dw_b, qdw_b);
    // 5) offsets + mask (im2col MFMA, K-split x2 in one grid)
    offmask_mfma<<<512, 256, 0, stream>>>(qdw_b, cwT_b, cb, om0, om1);
    // 6) precompute sample points (sums the two K-halves)
    precompute_pts<<<2304, 256, 0, stream>>>(om0, om1, pre);
    // 7) deformable attention (16 lanes/unit, packed f32x2 math)
    deform_attn<<<4096, 256, 0, stream>>>(qdw_b, pre, attn_b);
    // 8) projection (fp32 out)
    mfma_gemm<false, false><<<dim3(64, 4), 256, 0, stream>>>(attn_b, proj_wT_b, proj_b,
                                                             d_out, 8192, 256, 256);
}

// Round 11
// 172.784 us; speedup vs baseline: 1.9567x; 1.0026x over previous
//
#include <hip/hip_runtime.h>

typedef unsigned short u16;
typedef unsigned int u32;
typedef short bf16x8 __attribute__((ext_vector_type(8)));  // 8 bf16 (4 VGPRs)
typedef float f32x4 __attribute__((ext_vector_type(4)));
typedef float f32x2 __attribute__((ext_vector_type(2)));
typedef u32 u32x2 __attribute__((ext_vector_type(2)));

#define PP 4096
#define KPT 9

__device__ __forceinline__ u16 f2b(float f) {
    union { float f; unsigned int u; } v; v.f = f;
    unsigned int u = v.u;
    unsigned int r = u + 0x7FFFu + ((u >> 16) & 1u);   // RNE
    return (u16)(r >> 16);
}
__device__ __forceinline__ float b2f(u16 b) {
    union { unsigned int u; float f; } v; v.u = ((unsigned int)b) << 16;
    return v.f;
}
__device__ __forceinline__ f32x2 unpk2(u32 u) {
    f32x2 r;
    r.x = __uint_as_float(u << 16);
    r.y = __uint_as_float(u & 0xFFFF0000u);
    return r;
}

// ---- fused: weight transpose/convert (blocks 0..1023) + composite offset/mask
//      weight fold (blocks 1024..1791) ----
__global__ __launch_bounds__(256) void prep_weights(
        const float* __restrict__ qkv_w, const float* __restrict__ proj_w,
        const float* __restrict__ off_pconv_w, const float* __restrict__ off_w,
        const float* __restrict__ off_b, const float* __restrict__ mask_pconv_w,
        const float* __restrict__ mask_w, const float* __restrict__ mask_b,
        u16* __restrict__ qkv_wT_b, u16* __restrict__ proj_wT_b,
        u16* __restrict__ cwT_b, float* __restrict__ cb) {
    int blk = blockIdx.x;
    if (blk < 1024) {
        int idx = blk * 256 + threadIdx.x;     // 262144 total
        if (idx < 196608) {                    // qkv_w [256][768] -> T [768][256]
            int r = idx / 768, c = idx % 768;
            qkv_wT_b[c * 256 + r] = f2b(qkv_w[idx]);
        } else {
            int i3 = idx - 196608;             // proj_w [256][256] -> T
            int r = i3 >> 8, c = i3 & 255;
            proj_wT_b[c * 256 + r] = f2b(proj_w[i3]);
        }
        return;
    }
    int k = blk - 1024;      // 0..767
    int o = threadIdx.x;     // active 0..159
    if (o >= 160) return;
    float val = 0.f;
    if (o < 153) {
        if (k < 576) {
            int patch = k >> 6, i = k & 63;
            if (o < 144) {
                int g = o / 18, oo = o % 18;
                for (int c = 0; c < 64; c++)
                    val += off_w[(g * 18 + oo) * 256 + c] *
                           off_pconv_w[((g * 64 + c) * 64 + i) * 9 + patch];
            } else {
                int oo = o - 144;
                for (int c = 0; c < 64; c++)
                    val += mask_w[oo * 256 + c] * mask_pconv_w[(c * 64 + i) * 9 + patch];
            }
        } else {
            int j = k - 576;
            if (o < 144) {
                int g = o / 18, oo = o % 18;
                val = off_w[(g * 18 + oo) * 256 + 64 + j];
            } else {
                val = mask_w[(o - 144) * 256 + 64 + j];
            }
        }
    }
    cwT_b[o * 768 + k] = f2b(val);
    if (k == 0) {
        float bv = 0.f;
        if (o < 144) {
            int g = o / 18, oo = o % 18;
            const float PTSf[18] = {-1,-1,-1,0,-1,1,0,-1,0,0,0,1,1,-1,1,0,1,1};
            bv = off_b[g * 18 + oo] + PTSf[oo] * (float)(2 * g + 1);
        } else if (o < 153) {
            bv = mask_b[o - 144];
        }
        cb[o] = bv;
    }
}

// ---- generic MFMA GEMM: out = A[M][K] * BT[N][K]^T + bias, K compile-time ----
// BM=128, BN=64, BK=32, 256 threads (4 waves, 2x2), wave tile 64x32
template<bool OUT_BF16, bool A_F32, int KD>
__global__ __launch_bounds__(256) void mfma_gemm(
        const void* __restrict__ Av, const u16* __restrict__ BT,
        const float* __restrict__ bias, void* __restrict__ out, int N) {
    __shared__ u16 As[128][40];
    __shared__ u16 Bs[64][40];
    int tid = threadIdx.x;
    int row0 = blockIdx.x * 128, col0 = blockIdx.y * 64;
    int wid = tid >> 6, lane = tid & 63;
    int wr = wid >> 1, wc = wid & 1;
    int l15 = lane & 15, lhi = lane >> 4;
    f32x4 acc[4][2] = {};
    #pragma unroll
    for (int k0 = 0; k0 < KD; k0 += 32) {
        #pragma unroll
        for (int q = 0; q < 2; q++) {
            int idx = tid + q * 256;
            int r = idx >> 2, kc = (idx & 3) * 8;
            if (A_F32) {
                const float* Af = (const float*)Av;
                f32x4 a0 = *(const f32x4*)&Af[(size_t)(row0 + r) * KD + k0 + kc];
                f32x4 a1 = *(const f32x4*)&Af[(size_t)(row0 + r) * KD + k0 + kc + 4];
                bf16x8 v;
                #pragma unroll
                for (int j = 0; j < 4; j++) { v[j] = (short)f2b(a0[j]); v[4+j] = (short)f2b(a1[j]); }
                *(bf16x8*)&As[r][kc] = v;
            } else {
                const u16* Ab = (const u16*)Av;
                *(bf16x8*)&As[r][kc] = *(const bf16x8*)&Ab[(size_t)(row0 + r) * KD + k0 + kc];
            }
        }
        {
            int r = tid >> 2, kc = (tid & 3) * 8;
            *(bf16x8*)&Bs[r][kc] = *(const bf16x8*)&BT[(size_t)(col0 + r) * KD + k0 + kc];
        }
        __syncthreads();
        bf16x8 bfr[2];
        #pragma unroll
        for (int j = 0; j < 2; j++)
            bfr[j] = *(const bf16x8*)&Bs[wc * 32 + j * 16 + l15][lhi * 8];
        #pragma unroll
        for (int i = 0; i < 4; i++) {
            bf16x8 afr = *(const bf16x8*)&As[wr * 64 + i * 16 + l15][lhi * 8];
            #pragma unroll
            for (int j = 0; j < 2; j++)
                acc[i][j] = __builtin_amdgcn_mfma_f32_16x16x32_bf16(afr, bfr[j], acc[i][j], 0, 0, 0);
        }
        __syncthreads();
    }
    #pragma unroll
    for (int i = 0; i < 4; i++) {
        int row = row0 + wr * 64 + i * 16 + lhi * 4;
        #pragma unroll
        for (int j = 0; j < 2; j++) {
            int col = col0 + wc * 32 + j * 16 + l15;
            float bv = bias[col];
            #pragma unroll
            for (int r = 0; r < 4; r++) {
                float v = acc[i][j][r] + bv;
                if (OUT_BF16) ((u16*)out)[(size_t)(row + r) * N + col] = f2b(v);
                else          ((float*)out)[(size_t)(row + r) * N + col] = v;
            }
        }
    }
}

// ---- depthwise 3x3 (SAME), bf16 in/out, fp32 accum, 8 ch/thread ----
__global__ __launch_bounds__(256) void dwconv_b(const u16* __restrict__ qkv_b,
        const float* __restrict__ dww, const float* __restrict__ dwb,
        u16* __restrict__ out) {
    int idx = blockIdx.x * 256 + threadIdx.x;       // 8192*96
    int c8 = (idx % 96) * 8;
    int pix = idx / 96;
    int w = pix & 63, h = (pix >> 6) & 63, b = pix >> 12;
    float acc[8];
    #pragma unroll
    for (int j = 0; j < 8; j++) acc[j] = dwb[c8 + j];
    #pragma unroll
    for (int ky = 0; ky < 3; ky++) {
        int hh = h + ky - 1;
        if (hh < 0 || hh >= 64) continue;
        #pragma unroll
        for (int kx = 0; kx < 3; kx++) {
            int ww = w + kx - 1;
            if (ww < 0 || ww >= 64) continue;
            bf16x8 v = *(const bf16x8*)&qkv_b[((size_t)((b * 64 + hh) * 64 + ww)) * 768 + c8];
            #pragma unroll
            for (int j = 0; j < 8; j++)
                acc[j] += b2f((u16)v[j]) * dww[(ky * 3 + kx) * 768 + c8 + j];
        }
    }
    bf16x8 o;
    #pragma unroll
    for (int j = 0; j < 8; j++) o[j] = (short)f2b(acc[j]);
    *(bf16x8*)&out[(size_t)idx * 8] = o;
}

// ---- offsets+mask via im2col MFMA GEMM, K-split x2 for occupancy ----
// grid 512: blockIdx&1 = K-half (0: k[0,384)+bias -> om0, 1: k[384,768) -> om1)
__global__ __launch_bounds__(256) void offmask_mfma(const u16* __restrict__ qdw_b,
        const u16* __restrict__ cwT_b, const float* __restrict__ cb,
        float* __restrict__ om0, float* __restrict__ om1) {
    __shared__ u16 As[32][40];
    __shared__ u16 Bs[160][40];
    int tid = threadIdx.x;
    int half = blockIdx.x & 1;
    int p0 = (blockIdx.x >> 1) * 32;
    int kbeg = half ? 384 : 0;
    int kend = kbeg + 384;
    int wid = tid >> 6, lane = tid & 63;
    int wr = wid >> 1, wc = wid & 1;
    int l15 = lane & 15, lhi = lane >> 4;
    f32x4 acc[5] = {};
    for (int k0 = kbeg; k0 < kend; k0 += 32) {
        if (tid < 128) {
            int r = tid >> 2, kc = (tid & 3) * 8;
            int pixel = p0 + r;
            int w = pixel & 63, h = (pixel >> 6) & 63, b = pixel >> 12;
            bf16x8 v = {};
            if (k0 < 576) {
                int patch = k0 >> 6;
                int dy = patch / 3 - 1, dx = patch % 3 - 1;
                int hh = h + dy, ww = w + dx;
                if (hh >= 0 && hh < 64 && ww >= 0 && ww < 64)
                    v = *(const bf16x8*)&qdw_b[((size_t)((b * 64 + hh) * 64 + ww)) * 768 + (k0 & 63) + kc];
            } else {
                v = *(const bf16x8*)&qdw_b[((size_t)((b * 64 + h) * 64 + w)) * 768 + 64 + (k0 - 576) + kc];
            }
            *(bf16x8*)&As[r][kc] = v;
        }
        for (int idx = tid; idx < 640; idx += 256) {
            int r = idx >> 2, kc = (idx & 3) * 8;
            *(bf16x8*)&Bs[r][kc] = *(const bf16x8*)&cwT_b[r * 768 + k0 + kc];
        }
        __syncthreads();
        bf16x8 afr = *(const bf16x8*)&As[wr * 16 + l15][lhi * 8];
        #pragma unroll
        for (int j = 0; j < 5; j++) {
            bf16x8 bfr = *(const bf16x8*)&Bs[wc * 80 + j * 16 + l15][lhi * 8];
            acc[j] = __builtin_amdgcn_mfma_f32_16x16x32_bf16(afr, bfr, acc[j], 0, 0, 0);
        }
        __syncthreads();
    }
    float* dst = half ? om1 : om0;
    int row = p0 + wr * 16 + lhi * 4;
    #pragma unroll
    for (int j = 0; j < 5; j++) {
        int col = wc * 80 + j * 16 + l15;
        float bv = half ? 0.f : cb[col];
        #pragma unroll
        for (int r = 0; r < 4; r++)
            dst[(size_t)(row + r) * 160 + col] = acc[j][r] + bv;
    }
}

// ---- precompute per-(pix,g,k) sample params: packed corner idx + wx,wy,mask ----
// pre[pix*72 + g*9 + k] = {u32(idx00 | dxo<<16 | dyo<<17), wx, wy, mask}
__global__ __launch_bounds__(256) void precompute_pts(const float* __restrict__ om0,
        const float* __restrict__ om1, float4* __restrict__ pre) {
    int idx = blockIdx.x * 256 + threadIdx.x;      // 2*4096*72 = 589824 items
    if (idx >= 2 * PP * 72) return;
    int item = idx % 72;
    int pix = idx / 72;                            // b*4096 + p
    int g = item / 9, k = item % 9;
    int w = pix & 63, h = (pix >> 6) & 63;
    size_t rowb = (size_t)pix * 160;
    float dx = om0[rowb + g * 18 + 2 * k]     + om1[rowb + g * 18 + 2 * k];
    float dy = om0[rowb + g * 18 + 2 * k + 1] + om1[rowb + g * 18 + 2 * k + 1];
    float m  = om0[rowb + 144 + k]            + om1[rowb + 144 + k];
    float cx = fminf(fmaxf((float)w + dx, 0.f), 63.f);
    float cy = fminf(fmaxf((float)h + dy, 0.f), 63.f);
    float x0f = floorf(cx), y0f = floorf(cy);
    int x0 = (int)x0f, y0 = (int)y0f;
    u32 idx00 = (u32)((pix & ~4095) | (y0 << 6) | x0);   // corner pixel index
    u32 pk = idx00 | ((x0 < 63) ? 0x10000u : 0u) | ((y0 < 63) ? 0x20000u : 0u);
    float4 o;
    o.x = __uint_as_float(pk);
    o.y = cx - x0f;
    o.z = cy - y0f;
    o.w = m;
    pre[idx] = o;
}

// ---- deformable gather + softmax + weighted V sum ----
// 8 lanes per (b,g,p) unit, 4 channels/lane via 8-byte bf16-quad loads.
__global__ __launch_bounds__(256) void deform_attn(const u16* __restrict__ qdw_b,
        const float4* __restrict__ pre, u16* __restrict__ attn_b) {
    int tid = threadIdx.x;
    int unit = blockIdx.x * 32 + (tid >> 3);   // 65536 units, grid 2048
    int cl = tid & 7;                          // channel-quad lane
    int b = unit >> 15;
    int g = (unit >> 12) & 7;
    int p = unit & 4095;
    int pix = (b << 12) | p;
    const float scale = 0.17677669529663687f;  // 32^-0.5
    int c0 = g * 32 + 4 * cl;
    u32x2 qu = *(const u32x2*)&qdw_b[(size_t)pix * 768 + c0];
    f32x2 qa = unpk2(qu.x) * scale;
    f32x2 qb = unpk2(qu.y) * scale;
    const float4* pp = pre + (size_t)pix * 72 + g * 9;
    const char* base = (const char*)qdw_b;
    // byte offset of this lane's k-channel quad within a pixel row (row = 1536 B)
    u32 ckb = (u32)(512 + c0 * 2);
    float logit[KPT];
    f32x2 va[KPT], vb[KPT];
    #pragma unroll
    for (int k_ = 0; k_ < KPT; k_++) {
        float4 q4 = pp[k_];                       // uniform across the 8-lane group
        u32 pk = __float_as_uint(q4.x);
        float wx = q4.y, wy = q4.z, m = q4.w;
        u32 o00 = (pk & 0xFFFFu) * 1536u + ckb;
        u32 dX = (pk & 0x10000u) ? 1536u : 0u;
        u32 dY = (pk & 0x20000u) ? 98304u : 0u;
        u32 o01 = o00 + dX, o10 = o00 + dY, o11 = o00 + dY + dX;
        u32x2 K00 = *(const u32x2*)(base + o00);
        u32x2 V00 = *(const u32x2*)(base + o00 + 512);
        u32x2 K01 = *(const u32x2*)(base + o01);
        u32x2 V01 = *(const u32x2*)(base + o01 + 512);
        u32x2 K10 = *(const u32x2*)(base + o10);
        u32x2 V10 = *(const u32x2*)(base + o10 + 512);
        u32x2 K11 = *(const u32x2*)(base + o11);
        u32x2 V11 = *(const u32x2*)(base + o11 + 512);
        float w00 = (1.f - wx) * (1.f - wy), w01 = wx * (1.f - wy);
        float w10 = (1.f - wx) * wy,         w11 = wx * wy;
        f32x2 ka = unpk2(K00.x) * w00 + unpk2(K01.x) * w01
                 + unpk2(K10.x) * w10 + unpk2(K11.x) * w11;
        f32x2 kb = unpk2(K00.y) * w00 + unpk2(K01.y) * w01
                 + unpk2(K10.y) * w10 + unpk2(K11.y) * w11;
        f32x2 vva = unpk2(V00.x) * w00 + unpk2(V01.x) * w01
                  + unpk2(V10.x) * w10 + unpk2(V11.x) * w11;
        f32x2 vvb = unpk2(V00.y) * w00 + unpk2(V01.y) * w01
                  + unpk2(V10.y) * w10 + unpk2(V11.y) * w11;
        f32x2 pr = qa * ka + qb * kb;
        float part = pr.x + pr.y;
        part += __shfl_xor(part, 4);
        part += __shfl_xor(part, 2);
        part += __shfl_xor(part, 1);
        logit[k_] = part * m;
        va[k_] = vva * m;
        vb[k_] = vvb * m;
    }
    float mx = fmaxf(fmaxf(fmaxf(logit[0], logit[1]), fmaxf(logit[2], logit[3])),
                     fmaxf(fmaxf(logit[4], logit[5]),
                           fmaxf(fmaxf(logit[6], logit[7]), logit[8])));
    float s = 0.f;
    #pragma unroll
    for (int k_ = 0; k_ < KPT; k_++) { logit[k_] = __expf(logit[k_] - mx); s += logit[k_]; }
    float inv = 1.f / s;
    f32x2 oa = {0.f, 0.f}, ob = {0.f, 0.f};
    #pragma unroll
    for (int k_ = 0; k_ < KPT; k_++) { oa += va[k_] * logit[k_]; ob += vb[k_] * logit[k_]; }
    oa *= inv; ob *= inv;
    u32x2 outw;
    outw.x = (u32)f2b(oa.x) | ((u32)f2b(oa.y) << 16);
    outw.y = (u32)f2b(ob.x) | ((u32)f2b(ob.y) << 16);
    *(u32x2*)&attn_b[(size_t)pix * 256 + c0] = outw;
}

extern "C" void kernel_launch(void* const* d_in, const int* in_sizes, int n_in,
                              void* d_out, int out_size, void* d_ws, size_t ws_size,
                              hipStream_t stream) {
    const float* x            = (const float*)d_in[0];
    const float* qkv_w        = (const float*)d_in[1];
    const float* qkv_b        = (const float*)d_in[2];
    const float* dw_w         = (const float*)d_in[3];
    const float* dw_b         = (const float*)d_in[4];
    const float* off_pconv_w  = (const float*)d_in[5];
    const float* off_w        = (const float*)d_in[6];
    const float* off_b        = (const float*)d_in[7];
    const float* mask_pconv_w = (const float*)d_in[8];
    const float* mask_w       = (const float*)d_in[9];
    const float* mask_b       = (const float*)d_in[10];
    const float* proj_w       = (const float*)d_in[11];
    const float* proj_b       = (const float*)d_in[12];

    char* ws = (char*)d_ws;
    size_t off = 0;
    u16*   qkv_wT_b   = (u16*)(ws + off);                 off += 768ull*256*2;
    u16*   proj_wT_b  = (u16*)(ws + off);                 off += 256ull*256*2;
    u16*   qkv_bf     = (u16*)(ws + off);                 off += 8192ull*768*2;
    u16*   qdw_b      = (u16*)(ws + off);                 off += 8192ull*768*2;
    u16*   cwT_b      = (u16*)(ws + off);                 off += 160ull*768*2;
    float* cb         = (float*)(ws + off);               off += 256*4;
    float* om0        = (float*)(ws + off);               off += 8192ull*160*4;
    float* om1        = (float*)(ws + off);               off += 8192ull*160*4;
    u16*   attn_b     = (u16*)(ws + off);                 off += 8192ull*256*2;
    float4* pre       = (float4*)(ws + off);              off += 589824ull*16;

    // 1) weight convert/transpose + composite offset/mask weights (one launch)
    prep_weights<<<1792, 256, 0, stream>>>(qkv_w, proj_w, off_pconv_w, off_w, off_b,
                                           mask_pconv_w, mask_w, mask_b,
                                           qkv_wT_b, proj_wT_b, cwT_b, cb);
    // 2) qkv = x @ qkv_w + b   (fp32 A converted in staging, bf16 MFMA, bf16 out)
    mfma_gemm<true, true, 256><<<dim3(64, 12), 256, 0, stream>>>(x, qkv_wT_b, qkv_b,
                                                                 qkv_bf, 768);
    // 3) depthwise 3x3
    dwconv_b<<<3072, 256, 0, stream>>>(qkv_bf, dw_w, dw_b, qdw_b);
    // 4) offsets + mask (im2col MFMA, K-split x2 in one grid)
    offmask_mfma<<<512, 256, 0, stream>>>(qdw_b, cwT_b, cb, om0, om1);
    // 5) precompute sample points (sums the two K-halves)
    precompute_pts<<<2304, 256, 0, stream>>>(om0, om1, pre);
    // 6) deformable attention (8 lanes/unit, 4 ch/lane, 8B gathers)
    deform_attn<<<2048, 256, 0, stream>>>(qdw_b, pre, attn_b);
    // 7) projection (fp32 out)
    mfma_gemm<false, false, 256><<<dim3(64, 4), 256, 0, stream>>>(attn_b, proj_wT_b,
                                                                  proj_b, d_out, 256);
}

// Round 12
// 171.836 us; speedup vs baseline: 1.9675x; 1.0055x over previous
//
#include <hip/hip_runtime.h>

typedef unsigned short u16;
typedef unsigned int u32;
typedef short bf16x8 __attribute__((ext_vector_type(8)));  // 8 bf16 (4 VGPRs)
typedef float f32x4 __attribute__((ext_vector_type(4)));
typedef float f32x2 __attribute__((ext_vector_type(2)));
typedef u32 u32x2 __attribute__((ext_vector_type(2)));

#define PP 4096
#define KPT 9

__device__ __forceinline__ u16 f2b(float f) {
    union { float f; unsigned int u; } v; v.f = f;
    unsigned int u = v.u;
    unsigned int r = u + 0x7FFFu + ((u >> 16) & 1u);   // RNE
    return (u16)(r >> 16);
}
__device__ __forceinline__ float b2f(u16 b) {
    union { unsigned int u; float f; } v; v.u = ((unsigned int)b) << 16;
    return v.f;
}
__device__ __forceinline__ f32x2 unpk2(u32 u) {
    f32x2 r;
    r.x = __uint_as_float(u << 16);
    r.y = __uint_as_float(u & 0xFFFF0000u);
    return r;
}

// ---- fused: weight transpose/convert (blocks 0..1023) + composite offset/mask
//      weight fold (blocks 1024..1791) ----
__global__ __launch_bounds__(256) void prep_weights(
        const float* __restrict__ qkv_w, const float* __restrict__ proj_w,
        const float* __restrict__ off_pconv_w, const float* __restrict__ off_w,
        const float* __restrict__ off_b, const float* __restrict__ mask_pconv_w,
        const float* __restrict__ mask_w, const float* __restrict__ mask_b,
        u16* __restrict__ qkv_wT_b, u16* __restrict__ proj_wT_b,
        u16* __restrict__ cwT_b, float* __restrict__ cb) {
    int blk = blockIdx.x;
    if (blk < 1024) {
        int idx = blk * 256 + threadIdx.x;     // 262144 total
        if (idx < 196608) {                    // qkv_w [256][768] -> T [768][256]
            int r = idx / 768, c = idx % 768;
            qkv_wT_b[c * 256 + r] = f2b(qkv_w[idx]);
        } else {
            int i3 = idx - 196608;             // proj_w [256][256] -> T
            int r = i3 >> 8, c = i3 & 255;
            proj_wT_b[c * 256 + r] = f2b(proj_w[i3]);
        }
        return;
    }
    int k = blk - 1024;      // 0..767
    int o = threadIdx.x;     // active 0..159
    if (o >= 160) return;
    float val = 0.f;
    if (o < 153) {
        if (k < 576) {
            int patch = k >> 6, i = k & 63;
            if (o < 144) {
                int g = o / 18, oo = o % 18;
                for (int c = 0; c < 64; c++)
                    val += off_w[(g * 18 + oo) * 256 + c] *
                           off_pconv_w[((g * 64 + c) * 64 + i) * 9 + patch];
            } else {
                int oo = o - 144;
                for (int c = 0; c < 64; c++)
                    val += mask_w[oo * 256 + c] * mask_pconv_w[(c * 64 + i) * 9 + patch];
            }
        } else {
            int j = k - 576;
            if (o < 144) {
                int g = o / 18, oo = o % 18;
                val = off_w[(g * 18 + oo) * 256 + 64 + j];
            } else {
                val = mask_w[(o - 144) * 256 + 64 + j];
            }
        }
    }
    cwT_b[o * 768 + k] = f2b(val);
    if (k == 0) {
        float bv = 0.f;
        if (o < 144) {
            int g = o / 18, oo = o % 18;
            const float PTSf[18] = {-1,-1,-1,0,-1,1,0,-1,0,0,0,1,1,-1,1,0,1,1};
            bv = off_b[g * 18 + oo] + PTSf[oo] * (float)(2 * g + 1);
        } else if (o < 153) {
            bv = mask_b[o - 144];
        }
        cb[o] = bv;
    }
}

// ---- generic MFMA GEMM: out = A[M][K] * BT[N][K]^T + bias, K compile-time ----
// BM=64, BN=64, BK=32, 256 threads (4 waves, 2x2), wave tile 32x32
template<bool OUT_BF16, bool A_F32, int KD>
__global__ __launch_bounds__(256) void mfma_gemm(
        const void* __restrict__ Av, const u16* __restrict__ BT,
        const float* __restrict__ bias, void* __restrict__ out, int N) {
    __shared__ u16 As[64][40];
    __shared__ u16 Bs[64][40];
    int tid = threadIdx.x;
    int row0 = blockIdx.x * 64, col0 = blockIdx.y * 64;
    int wid = tid >> 6, lane = tid & 63;
    int wr = wid >> 1, wc = wid & 1;
    int l15 = lane & 15, lhi = lane >> 4;
    f32x4 acc[2][2] = {};
    #pragma unroll
    for (int k0 = 0; k0 < KD; k0 += 32) {
        {
            int r = tid >> 2, kc = (tid & 3) * 8;
            if (A_F32) {
                const float* Af = (const float*)Av;
                f32x4 a0 = *(const f32x4*)&Af[(size_t)(row0 + r) * KD + k0 + kc];
                f32x4 a1 = *(const f32x4*)&Af[(size_t)(row0 + r) * KD + k0 + kc + 4];
                bf16x8 v;
                #pragma unroll
                for (int j = 0; j < 4; j++) { v[j] = (short)f2b(a0[j]); v[4+j] = (short)f2b(a1[j]); }
                *(bf16x8*)&As[r][kc] = v;
            } else {
                const u16* Ab = (const u16*)Av;
                *(bf16x8*)&As[r][kc] = *(const bf16x8*)&Ab[(size_t)(row0 + r) * KD + k0 + kc];
            }
            *(bf16x8*)&Bs[r][kc] = *(const bf16x8*)&BT[(size_t)(col0 + r) * KD + k0 + kc];
        }
        __syncthreads();
        bf16x8 bfr[2], afr[2];
        #pragma unroll
        for (int j = 0; j < 2; j++) {
            bfr[j] = *(const bf16x8*)&Bs[wc * 32 + j * 16 + l15][lhi * 8];
            afr[j] = *(const bf16x8*)&As[wr * 32 + j * 16 + l15][lhi * 8];
        }
        #pragma unroll
        for (int i = 0; i < 2; i++)
            #pragma unroll
            for (int j = 0; j < 2; j++)
                acc[i][j] = __builtin_amdgcn_mfma_f32_16x16x32_bf16(afr[i], bfr[j], acc[i][j], 0, 0, 0);
        __syncthreads();
    }
    #pragma unroll
    for (int i = 0; i < 2; i++) {
        int row = row0 + wr * 32 + i * 16 + lhi * 4;
        #pragma unroll
        for (int j = 0; j < 2; j++) {
            int col = col0 + wc * 32 + j * 16 + l15;
            float bv = bias[col];
            #pragma unroll
            for (int r = 0; r < 4; r++) {
                float v = acc[i][j][r] + bv;
                if (OUT_BF16) ((u16*)out)[(size_t)(row + r) * N + col] = f2b(v);
                else          ((float*)out)[(size_t)(row + r) * N + col] = v;
            }
        }
    }
}

// ---- depthwise 3x3 (SAME), bf16 in/out, fp32 accum, 8 ch/thread ----
__global__ __launch_bounds__(256) void dwconv_b(const u16* __restrict__ qkv_b,
        const float* __restrict__ dww, const float* __restrict__ dwb,
        u16* __restrict__ out) {
    int idx = blockIdx.x * 256 + threadIdx.x;       // 8192*96
    int c8 = (idx % 96) * 8;
    int pix = idx / 96;
    int w = pix & 63, h = (pix >> 6) & 63, b = pix >> 12;
    float acc[8];
    #pragma unroll
    for (int j = 0; j < 8; j++) acc[j] = dwb[c8 + j];
    #pragma unroll
    for (int ky = 0; ky < 3; ky++) {
        int hh = h + ky - 1;
        if (hh < 0 || hh >= 64) continue;
        #pragma unroll
        for (int kx = 0; kx < 3; kx++) {
            int ww = w + kx - 1;
            if (ww < 0 || ww >= 64) continue;
            bf16x8 v = *(const bf16x8*)&qkv_b[((size_t)((b * 64 + hh) * 64 + ww)) * 768 + c8];
            #pragma unroll
            for (int j = 0; j < 8; j++)
                acc[j] += b2f((u16)v[j]) * dww[(ky * 3 + kx) * 768 + c8 + j];
        }
    }
    bf16x8 o;
    #pragma unroll
    for (int j = 0; j < 8; j++) o[j] = (short)f2b(acc[j]);
    *(bf16x8*)&out[(size_t)idx * 8] = o;
}

// ---- offsets+mask via im2col MFMA GEMM, K-split x2 for occupancy ----
// grid 512: blockIdx&1 = K-half (0: k[0,384)+bias -> om0, 1: k[384,768) -> om1)
__global__ __launch_bounds__(256) void offmask_mfma(const u16* __restrict__ qdw_b,
        const u16* __restrict__ cwT_b, const float* __restrict__ cb,
        float* __restrict__ om0, float* __restrict__ om1) {
    __shared__ u16 As[32][40];
    __shared__ u16 Bs[160][40];
    int tid = threadIdx.x;
    int half = blockIdx.x & 1;
    int p0 = (blockIdx.x >> 1) * 32;
    int kbeg = half ? 384 : 0;
    int kend = kbeg + 384;
    int wid = tid >> 6, lane = tid & 63;
    int wr = wid >> 1, wc = wid & 1;
    int l15 = lane & 15, lhi = lane >> 4;
    f32x4 acc[5] = {};
    for (int k0 = kbeg; k0 < kend; k0 += 32) {
        if (tid < 128) {
            int r = tid >> 2, kc = (tid & 3) * 8;
            int pixel = p0 + r;
            int w = pixel & 63, h = (pixel >> 6) & 63, b = pixel >> 12;
            bf16x8 v = {};
            if (k0 < 576) {
                int patch = k0 >> 6;
                int dy = patch / 3 - 1, dx = patch % 3 - 1;
                int hh = h + dy, ww = w + dx;
                if (hh >= 0 && hh < 64 && ww >= 0 && ww < 64)
                    v = *(const bf16x8*)&qdw_b[((size_t)((b * 64 + hh) * 64 + ww)) * 768 + (k0 & 63) + kc];
            } else {
                v = *(const bf16x8*)&qdw_b[((size_t)((b * 64 + h) * 64 + w)) * 768 + 64 + (k0 - 576) + kc];
            }
            *(bf16x8*)&As[r][kc] = v;
        }
        for (int idx = tid; idx < 640; idx += 256) {
            int r = idx >> 2, kc = (idx & 3) * 8;
            *(bf16x8*)&Bs[r][kc] = *(const bf16x8*)&cwT_b[r * 768 + k0 + kc];
        }
        __syncthreads();
        bf16x8 afr = *(const bf16x8*)&As[wr * 16 + l15][lhi * 8];
        #pragma unroll
        for (int j = 0; j < 5; j++) {
            bf16x8 bfr = *(const bf16x8*)&Bs[wc * 80 + j * 16 + l15][lhi * 8];
            acc[j] = __builtin_amdgcn_mfma_f32_16x16x32_bf16(afr, bfr, acc[j], 0, 0, 0);
        }
        __syncthreads();
    }
    float* dst = half ? om1 : om0;
    int row = p0 + wr * 16 + lhi * 4;
    #pragma unroll
    for (int j = 0; j < 5; j++) {
        int col = wc * 80 + j * 16 + l15;
        float bv = half ? 0.f : cb[col];
        #pragma unroll
        for (int r = 0; r < 4; r++)
            dst[(size_t)(row + r) * 160 + col] = acc[j][r] + bv;
    }
}

// ---- precompute per-(pix,g,k) sample params: packed corner idx + wx,wy,mask ----
// pre[pix*72 + g*9 + k] = {u32(idx00 | dxo<<16 | dyo<<17), wx, wy, mask}
__global__ __launch_bounds__(256) void precompute_pts(const float* __restrict__ om0,
        const float* __restrict__ om1, float4* __restrict__ pre) {
    int idx = blockIdx.x * 256 + threadIdx.x;      // 2*4096*72 = 589824 items
    if (idx >= 2 * PP * 72) return;
    int item = idx % 72;
    int pix = idx / 72;                            // b*4096 + p
    int g = item / 9, k = item % 9;
    int w = pix & 63, h = (pix >> 6) & 63;
    size_t rowb = (size_t)pix * 160;
    float dx = om0[rowb + g * 18 + 2 * k]     + om1[rowb + g * 18 + 2 * k];
    float dy = om0[rowb + g * 18 + 2 * k + 1] + om1[rowb + g * 18 + 2 * k + 1];
    float m  = om0[rowb + 144 + k]            + om1[rowb + 144 + k];
    float cx = fminf(fmaxf((float)w + dx, 0.f), 63.f);
    float cy = fminf(fmaxf((float)h + dy, 0.f), 63.f);
    float x0f = floorf(cx), y0f = floorf(cy);
    int x0 = (int)x0f, y0 = (int)y0f;
    u32 idx00 = (u32)((pix & ~4095) | (y0 << 6) | x0);   // corner pixel index
    u32 pk = idx00 | ((x0 < 63) ? 0x10000u : 0u) | ((y0 < 63) ? 0x20000u : 0u);
    float4 o;
    o.x = __uint_as_float(pk);
    o.y = cx - x0f;
    o.z = cy - y0f;
    o.w = m;
    pre[idx] = o;
}

// ---- deformable gather + softmax + weighted V sum ----
// Block = 4 pixels x 8 groups (32 units x 8 lanes); XCD-chunked block swizzle
// so each XCD works a contiguous pixel band -> K/V gathers L2-resident.
__global__ __launch_bounds__(256) void deform_attn(const u16* __restrict__ qdw_b,
        const float4* __restrict__ pre, u16* __restrict__ attn_b) {
    int tid = threadIdx.x;
    int bid = blockIdx.x;                       // grid 2048 (%8==0)
    int sbid = (bid & 7) * 256 + (bid >> 3);    // bijective XCD-chunked swizzle
    int t = tid >> 3;                           // unit-in-block 0..31
    int cl = tid & 7;                           // channel-quad lane
    int g = t & 7;
    int pix = sbid * 4 + (t >> 3);              // 4 consecutive pixels per block
    const float scale = 0.17677669529663687f;   // 32^-0.5
    int c0 = g * 32 + 4 * cl;
    u32x2 qu = *(const u32x2*)&qdw_b[(size_t)pix * 768 + c0];
    f32x2 qa = unpk2(qu.x) * scale;
    f32x2 qb = unpk2(qu.y) * scale;
    const float4* pp = pre + (size_t)pix * 72 + g * 9;
    const char* base = (const char*)qdw_b;
    // byte offset of this lane's k-channel quad within a pixel row (row = 1536 B)
    u32 ckb = (u32)(512 + c0 * 2);
    float logit[KPT];
    f32x2 va[KPT], vb[KPT];
    #pragma unroll
    for (int k_ = 0; k_ < KPT; k_++) {
        float4 q4 = pp[k_];                       // uniform across the 8-lane group
        u32 pk = __float_as_uint(q4.x);
        float wx = q4.y, wy = q4.z, m = q4.w;
        u32 o00 = (pk & 0xFFFFu) * 1536u + ckb;
        u32 dX = (pk & 0x10000u) ? 1536u : 0u;
        u32 dY = (pk & 0x20000u) ? 98304u : 0u;
        u32 o01 = o00 + dX, o10 = o00 + dY, o11 = o00 + dY + dX;
        u32x2 K00 = *(const u32x2*)(base + o00);
        u32x2 V00 = *(const u32x2*)(base + o00 + 512);
        u32x2 K01 = *(const u32x2*)(base + o01);
        u32x2 V01 = *(const u32x2*)(base + o01 + 512);
        u32x2 K10 = *(const u32x2*)(base + o10);
        u32x2 V10 = *(const u32x2*)(base + o10 + 512);
        u32x2 K11 = *(const u32x2*)(base + o11);
        u32x2 V11 = *(const u32x2*)(base + o11 + 512);
        float w00 = (1.f - wx) * (1.f - wy), w01 = wx * (1.f - wy);
        float w10 = (1.f - wx) * wy,         w11 = wx * wy;
        f32x2 ka = unpk2(K00.x) * w00 + unpk2(K01.x) * w01
                 + unpk2(K10.x) * w10 + unpk2(K11.x) * w11;
        f32x2 kb = unpk2(K00.y) * w00 + unpk2(K01.y) * w01
                 + unpk2(K10.y) * w10 + unpk2(K11.y) * w11;
        f32x2 vva = unpk2(V00.x) * w00 + unpk2(V01.x) * w01
                  + unpk2(V10.x) * w10 + unpk2(V11.x) * w11;
        f32x2 vvb = unpk2(V00.y) * w00 + unpk2(V01.y) * w01
                  + unpk2(V10.y) * w10 + unpk2(V11.y) * w11;
        f32x2 pr = qa * ka + qb * kb;
        float part = pr.x + pr.y;
        part += __shfl_xor(part, 4);
        part += __shfl_xor(part, 2);
        part += __shfl_xor(part, 1);
        logit[k_] = part * m;
        va[k_] = vva * m;
        vb[k_] = vvb * m;
    }
    float mx = fmaxf(fmaxf(fmaxf(logit[0], logit[1]), fmaxf(logit[2], logit[3])),
                     fmaxf(fmaxf(logit[4], logit[5]),
                           fmaxf(fmaxf(logit[6], logit[7]), logit[8])));
    float s = 0.f;
    #pragma unroll
    for (int k_ = 0; k_ < KPT; k_++) { logit[k_] = __expf(logit[k_] - mx); s += logit[k_]; }
    float inv = 1.f / s;
    f32x2 oa = {0.f, 0.f}, ob = {0.f, 0.f};
    #pragma unroll
    for (int k_ = 0; k_ < KPT; k_++) { oa += va[k_] * logit[k_]; ob += vb[k_] * logit[k_]; }
    oa *= inv; ob *= inv;
    u32x2 outw;
    outw.x = (u32)f2b(oa.x) | ((u32)f2b(oa.y) << 16);
    outw.y = (u32)f2b(ob.x) | ((u32)f2b(ob.y) << 16);
    *(u32x2*)&attn_b[(size_t)pix * 256 + c0] = outw;
}

extern "C" void kernel_launch(void* const* d_in, const int* in_sizes, int n_in,
                              void* d_out, int out_size, void* d_ws, size_t ws_size,
                              hipStream_t stream) {
    const float* x            = (const float*)d_in[0];
    const float* qkv_w        = (const float*)d_in[1];
    const float* qkv_b        = (const float*)d_in[2];
    const float* dw_w         = (const float*)d_in[3];
    const float* dw_b         = (const float*)d_in[4];
    const float* off_pconv_w  = (const float*)d_in[5];
    const float* off_w        = (const float*)d_in[6];
    const float* off_b        = (const float*)d_in[7];
    const float* mask_pconv_w = (const float*)d_in[8];
    const float* mask_w       = (const float*)d_in[9];
    const float* mask_b       = (const float*)d_in[10];
    const float* proj_w       = (const float*)d_in[11];
    const float* proj_b       = (const float*)d_in[12];

    char* ws = (char*)d_ws;
    size_t off = 0;
    u16*   qkv_wT_b   = (u16*)(ws + off);                 off += 768ull*256*2;
    u16*   proj_wT_b  = (u16*)(ws + off);                 off += 256ull*256*2;
    u16*   qkv_bf     = (u16*)(ws + off);                 off += 8192ull*768*2;
    u16*   qdw_b      = (u16*)(ws + off);                 off += 8192ull*768*2;
    u16*   cwT_b      = (u16*)(ws + off);                 off += 160ull*768*2;
    float* cb         = (float*)(ws + off);               off += 256*4;
    float* om0        = (float*)(ws + off);               off += 8192ull*160*4;
    float* om1        = (float*)(ws + off);               off += 8192ull*160*4;
    u16*   attn_b     = (u16*)(ws + off);                 off += 8192ull*256*2;
    float4* pre       = (float4*)(ws + off);              off += 589824ull*16;

    // 1) weight convert/transpose + composite offset/mask weights (one launch)
    prep_weights<<<1792, 256, 0, stream>>>(qkv_w, proj_w, off_pconv_w, off_w, off_b,
                                           mask_pconv_w, mask_w, mask_b,
                                           qkv_wT_b, proj_wT_b, cwT_b, cb);
    // 2) qkv = x @ qkv_w + b   (fp32 A converted in staging, bf16 MFMA, bf16 out)
    mfma_gemm<true, true, 256><<<dim3(128, 12), 256, 0, stream>>>(x, qkv_wT_b, qkv_b,
                                                                  qkv_bf, 768);
    // 3) depthwise 3x3
    dwconv_b<<<3072, 256, 0, stream>>>(qkv_bf, dw_w, dw_b, qdw_b);
    // 4) offsets + mask (im2col MFMA, K-split x2 in one grid)
    offmask_mfma<<<512, 256, 0, stream>>>(qdw_b, cwT_b, cb, om0, om1);
    // 5) precompute sample points (sums the two K-halves)
    precompute_pts<<<2304, 256, 0, stream>>>(om0, om1, pre);
    // 6) deformable attention (4 px x 8 g per block, XCD-chunked swizzle)
    deform_attn<<<2048, 256, 0, stream>>>(qdw_b, pre, attn_b);
    // 7) projection (fp32 out)
    mfma_gemm<false, false, 256><<<dim3(128, 4), 256, 0, stream>>>(attn_b, proj_wT_b,
                                                                   proj_b, d_out, 256);
}

// Round 13
// 162.752 us; speedup vs baseline: 2.0773x; 1.0558x over previous
//
#include <hip/hip_runtime.h>

typedef unsigned short u16;
typedef unsigned int u32;
typedef short bf16x8 __attribute__((ext_vector_type(8)));  // 8 bf16 (4 VGPRs)
typedef float f32x4 __attribute__((ext_vector_type(4)));
typedef float f32x2 __attribute__((ext_vector_type(2)));
typedef u32 u32x2 __attribute__((ext_vector_type(2)));

#define PP 4096
#define KPT 9

__device__ __forceinline__ u16 f2b(float f) {
    union { float f; unsigned int u; } v; v.f = f;
    unsigned int u = v.u;
    unsigned int r = u + 0x7FFFu + ((u >> 16) & 1u);   // RNE
    return (u16)(r >> 16);
}
__device__ __forceinline__ float b2f(u16 b) {
    union { unsigned int u; float f; } v; v.u = ((unsigned int)b) << 16;
    return v.f;
}
__device__ __forceinline__ f32x2 unpk2(u32 u) {
    f32x2 r;
    r.x = __uint_as_float(u << 16);
    r.y = __uint_as_float(u & 0xFFFF0000u);
    return r;
}

// ---- fused: weight transpose/convert (blocks 0..1023) + composite offset/mask
//      weight fold (blocks 1024..1791) ----
__global__ __launch_bounds__(256) void prep_weights(
        const float* __restrict__ qkv_w, const float* __restrict__ proj_w,
        const float* __restrict__ off_pconv_w, const float* __restrict__ off_w,
        const float* __restrict__ off_b, const float* __restrict__ mask_pconv_w,
        const float* __restrict__ mask_w, const float* __restrict__ mask_b,
        u16* __restrict__ qkv_wT_b, u16* __restrict__ proj_wT_b,
        u16* __restrict__ cwT_b, float* __restrict__ cb) {
    int blk = blockIdx.x;
    if (blk < 1024) {
        int idx = blk * 256 + threadIdx.x;     // 262144 total
        if (idx < 196608) {                    // qkv_w [256][768] -> T [768][256]
            int r = idx / 768, c = idx % 768;
            qkv_wT_b[c * 256 + r] = f2b(qkv_w[idx]);
        } else {
            int i3 = idx - 196608;             // proj_w [256][256] -> T
            int r = i3 >> 8, c = i3 & 255;
            proj_wT_b[c * 256 + r] = f2b(proj_w[i3]);
        }
        return;
    }
    int k = blk - 1024;      // 0..767
    int o = threadIdx.x;     // active 0..159
    if (o >= 160) return;
    float val = 0.f;
    if (o < 153) {
        if (k < 576) {
            int patch = k >> 6, i = k & 63;
            if (o < 144) {
                int g = o / 18, oo = o % 18;
                for (int c = 0; c < 64; c++)
                    val += off_w[(g * 18 + oo) * 256 + c] *
                           off_pconv_w[((g * 64 + c) * 64 + i) * 9 + patch];
            } else {
                int oo = o - 144;
                for (int c = 0; c < 64; c++)
                    val += mask_w[oo * 256 + c] * mask_pconv_w[(c * 64 + i) * 9 + patch];
            }
        } else {
            int j = k - 576;
            if (o < 144) {
                int g = o / 18, oo = o % 18;
                val = off_w[(g * 18 + oo) * 256 + 64 + j];
            } else {
                val = mask_w[(o - 144) * 256 + 64 + j];
            }
        }
    }
    cwT_b[o * 768 + k] = f2b(val);
    if (k == 0) {
        float bv = 0.f;
        if (o < 144) {
            int g = o / 18, oo = o % 18;
            const float PTSf[18] = {-1,-1,-1,0,-1,1,0,-1,0,0,0,1,1,-1,1,0,1,1};
            bv = off_b[g * 18 + oo] + PTSf[oo] * (float)(2 * g + 1);
        } else if (o < 153) {
            bv = mask_b[o - 144];
        }
        cb[o] = bv;
    }
}

// ---- generic MFMA GEMM: out = A[M][K] * BT[N][K]^T + bias, K compile-time ----
// BM=64, BN=64, BK=32, 256 threads (4 waves, 2x2), wave tile 32x32
template<bool OUT_BF16, bool A_F32, int KD>
__global__ __launch_bounds__(256) void mfma_gemm(
        const void* __restrict__ Av, const u16* __restrict__ BT,
        const float* __restrict__ bias, void* __restrict__ out, int N) {
    __shared__ u16 As[64][40];
    __shared__ u16 Bs[64][40];
    int tid = threadIdx.x;
    int row0 = blockIdx.x * 64, col0 = blockIdx.y * 64;
    int wid = tid >> 6, lane = tid & 63;
    int wr = wid >> 1, wc = wid & 1;
    int l15 = lane & 15, lhi = lane >> 4;
    f32x4 acc[2][2] = {};
    #pragma unroll
    for (int k0 = 0; k0 < KD; k0 += 32) {
        {
            int r = tid >> 2, kc = (tid & 3) * 8;
            if (A_F32) {
                const float* Af = (const float*)Av;
                f32x4 a0 = *(const f32x4*)&Af[(size_t)(row0 + r) * KD + k0 + kc];
                f32x4 a1 = *(const f32x4*)&Af[(size_t)(row0 + r) * KD + k0 + kc + 4];
                bf16x8 v;
                #pragma unroll
                for (int j = 0; j < 4; j++) { v[j] = (short)f2b(a0[j]); v[4+j] = (short)f2b(a1[j]); }
                *(bf16x8*)&As[r][kc] = v;
            } else {
                const u16* Ab = (const u16*)Av;
                *(bf16x8*)&As[r][kc] = *(const bf16x8*)&Ab[(size_t)(row0 + r) * KD + k0 + kc];
            }
            *(bf16x8*)&Bs[r][kc] = *(const bf16x8*)&BT[(size_t)(col0 + r) * KD + k0 + kc];
        }
        __syncthreads();
        bf16x8 bfr[2], afr[2];
        #pragma unroll
        for (int j = 0; j < 2; j++) {
            bfr[j] = *(const bf16x8*)&Bs[wc * 32 + j * 16 + l15][lhi * 8];
            afr[j] = *(const bf16x8*)&As[wr * 32 + j * 16 + l15][lhi * 8];
        }
        #pragma unroll
        for (int i = 0; i < 2; i++)
            #pragma unroll
            for (int j = 0; j < 2; j++)
                acc[i][j] = __builtin_amdgcn_mfma_f32_16x16x32_bf16(afr[i], bfr[j], acc[i][j], 0, 0, 0);
        __syncthreads();
    }
    #pragma unroll
    for (int i = 0; i < 2; i++) {
        int row = row0 + wr * 32 + i * 16 + lhi * 4;
        #pragma unroll
        for (int j = 0; j < 2; j++) {
            int col = col0 + wc * 32 + j * 16 + l15;
            float bv = bias[col];
            #pragma unroll
            for (int r = 0; r < 4; r++) {
                float v = acc[i][j][r] + bv;
                if (OUT_BF16) ((u16*)out)[(size_t)(row + r) * N + col] = f2b(v);
                else          ((float*)out)[(size_t)(row + r) * N + col] = v;
            }
        }
    }
}

// ---- depthwise 3x3 (SAME), bf16 in/out, fp32 accum, 8 ch/thread ----
__global__ __launch_bounds__(256) void dwconv_b(const u16* __restrict__ qkv_b,
        const float* __restrict__ dww, const float* __restrict__ dwb,
        u16* __restrict__ out) {
    int idx = blockIdx.x * 256 + threadIdx.x;       // 8192*96
    int c8 = (idx % 96) * 8;
    int pix = idx / 96;
    int w = pix & 63, h = (pix >> 6) & 63, b = pix >> 12;
    float acc[8];
    #pragma unroll
    for (int j = 0; j < 8; j++) acc[j] = dwb[c8 + j];
    #pragma unroll
    for (int ky = 0; ky < 3; ky++) {
        int hh = h + ky - 1;
        if (hh < 0 || hh >= 64) continue;
        #pragma unroll
        for (int kx = 0; kx < 3; kx++) {
            int ww = w + kx - 1;
            if (ww < 0 || ww >= 64) continue;
            bf16x8 v = *(const bf16x8*)&qkv_b[((size_t)((b * 64 + hh) * 64 + ww)) * 768 + c8];
            #pragma unroll
            for (int j = 0; j < 8; j++)
                acc[j] += b2f((u16)v[j]) * dww[(ky * 3 + kx) * 768 + c8 + j];
        }
    }
    bf16x8 o;
    #pragma unroll
    for (int j = 0; j < 8; j++) o[j] = (short)f2b(acc[j]);
    *(bf16x8*)&out[(size_t)idx * 8] = o;
}

// ---- offsets+mask via im2col MFMA GEMM, K-split x4 for occupancy ----
// grid 1024: blockIdx&3 = K-quarter (quarter 0 adds bias -> om0; others -> om1..3)
__global__ __launch_bounds__(256) void offmask_mfma(const u16* __restrict__ qdw_b,
        const u16* __restrict__ cwT_b, const float* __restrict__ cb,
        float* __restrict__ om0, float* __restrict__ om1,
        float* __restrict__ om2, float* __restrict__ om3) {
    __shared__ u16 As[32][40];
    __shared__ u16 Bs[160][40];
    int tid = threadIdx.x;
    int half = blockIdx.x & 3;
    int p0 = (blockIdx.x >> 2) * 32;
    int kbeg = half * 192;
    int kend = kbeg + 192;
    int wid = tid >> 6, lane = tid & 63;
    int wr = wid >> 1, wc = wid & 1;
    int l15 = lane & 15, lhi = lane >> 4;
    f32x4 acc[5] = {};
    for (int k0 = kbeg; k0 < kend; k0 += 32) {
        if (tid < 128) {
            int r = tid >> 2, kc = (tid & 3) * 8;
            int pixel = p0 + r;
            int w = pixel & 63, h = (pixel >> 6) & 63, b = pixel >> 12;
            bf16x8 v = {};
            if (k0 < 576) {
                int patch = k0 >> 6;
                int dy = patch / 3 - 1, dx = patch % 3 - 1;
                int hh = h + dy, ww = w + dx;
                if (hh >= 0 && hh < 64 && ww >= 0 && ww < 64)
                    v = *(const bf16x8*)&qdw_b[((size_t)((b * 64 + hh) * 64 + ww)) * 768 + (k0 & 63) + kc];
            } else {
                v = *(const bf16x8*)&qdw_b[((size_t)((b * 64 + h) * 64 + w)) * 768 + 64 + (k0 - 576) + kc];
            }
            *(bf16x8*)&As[r][kc] = v;
        }
        for (int idx = tid; idx < 640; idx += 256) {
            int r = idx >> 2, kc = (idx & 3) * 8;
            *(bf16x8*)&Bs[r][kc] = *(const bf16x8*)&cwT_b[r * 768 + k0 + kc];
        }
        __syncthreads();
        bf16x8 afr = *(const bf16x8*)&As[wr * 16 + l15][lhi * 8];
        #pragma unroll
        for (int j = 0; j < 5; j++) {
            bf16x8 bfr = *(const bf16x8*)&Bs[wc * 80 + j * 16 + l15][lhi * 8];
            acc[j] = __builtin_amdgcn_mfma_f32_16x16x32_bf16(afr, bfr, acc[j], 0, 0, 0);
        }
        __syncthreads();
    }
    float* dst = (half == 0) ? om0 : (half == 1) ? om1 : (half == 2) ? om2 : om3;
    int row = p0 + wr * 16 + lhi * 4;
    #pragma unroll
    for (int j = 0; j < 5; j++) {
        int col = wc * 80 + j * 16 + l15;
        float bv = (half == 0) ? cb[col] : 0.f;
        #pragma unroll
        for (int r = 0; r < 4; r++)
            dst[(size_t)(row + r) * 160 + col] = acc[j][r] + bv;
    }
}

// ---- per-(pix,g,k) sample params from the 4 K-split partials ----
__device__ __forceinline__ float4 pt_params(const float* __restrict__ om0,
        const float* __restrict__ om1, const float* __restrict__ om2,
        const float* __restrict__ om3, int pix, int g, int k) {
    int w = pix & 63, h = (pix >> 6) & 63;
    size_t rowb = (size_t)pix * 160;
    size_t db = rowb + g * 18 + 2 * k;
    f32x2 d0 = *(const f32x2*)&om0[db];
    f32x2 d1 = *(const f32x2*)&om1[db];
    f32x2 d2 = *(const f32x2*)&om2[db];
    f32x2 d3 = *(const f32x2*)&om3[db];
    float m = om0[rowb + 144 + k] + om1[rowb + 144 + k]
            + om2[rowb + 144 + k] + om3[rowb + 144 + k];
    float dx = d0.x + d1.x + d2.x + d3.x;
    float dy = d0.y + d1.y + d2.y + d3.y;
    float cx = fminf(fmaxf((float)w + dx, 0.f), 63.f);
    float cy = fminf(fmaxf((float)h + dy, 0.f), 63.f);
    float x0f = floorf(cx), y0f = floorf(cy);
    int x0 = (int)x0f, y0 = (int)y0f;
    u32 pk = (u32)((pix & ~4095) | (y0 << 6) | x0)
           | ((x0 < 63) ? 0x10000u : 0u) | ((y0 < 63) ? 0x20000u : 0u);
    float4 o;
    o.x = __uint_as_float(pk);
    o.y = cx - x0f;
    o.z = cy - y0f;
    o.w = m;
    return o;
}

// ---- deformable gather + softmax + weighted V sum (point-params fused) ----
// Block = 4 pixels x 8 groups (32 units x 8 lanes); XCD-chunked block swizzle.
// Phase 1: block computes its 288 point-params into LDS. Phase 2: gather.
__global__ __launch_bounds__(256) void deform_attn(const u16* __restrict__ qdw_b,
        const float* __restrict__ om0, const float* __restrict__ om1,
        const float* __restrict__ om2, const float* __restrict__ om3,
        u16* __restrict__ attn_b) {
    __shared__ float4 ptp[288];
    int tid = threadIdx.x;
    int bid = blockIdx.x;                       // grid 2048 (%8==0)
    int sbid = (bid & 7) * 256 + (bid >> 3);    // bijective XCD-chunked swizzle
    // phase 1: 288 point-params (32 units x 9 points)
    for (int j = tid; j < 288; j += 256) {
        int u = j / 9, k = j % 9;
        int ppix = sbid * 4 + (u >> 3);
        ptp[j] = pt_params(om0, om1, om2, om3, ppix, u & 7, k);
    }
    __syncthreads();
    int t = tid >> 3;                           // unit-in-block 0..31
    int cl = tid & 7;                           // channel-quad lane
    int g = t & 7;
    int pix = sbid * 4 + (t >> 3);              // 4 consecutive pixels per block
    const float scale = 0.17677669529663687f;   // 32^-0.5
    int c0 = g * 32 + 4 * cl;
    u32x2 qu = *(const u32x2*)&qdw_b[(size_t)pix * 768 + c0];
    f32x2 qa = unpk2(qu.x) * scale;
    f32x2 qb = unpk2(qu.y) * scale;
    const char* base = (const char*)qdw_b;
    // byte offset of this lane's k-channel quad within a pixel row (row = 1536 B)
    u32 ckb = (u32)(512 + c0 * 2);
    float logit[KPT];
    f32x2 va[KPT], vb[KPT];
    #pragma unroll
    for (int k_ = 0; k_ < KPT; k_++) {
        float4 q4 = ptp[t * 9 + k_];              // uniform across the 8-lane group
        u32 pk = __float_as_uint(q4.x);
        float wx = q4.y, wy = q4.z, m = q4.w;
        u32 o00 = (pk & 0xFFFFu) * 1536u + ckb;
        u32 dX = (pk & 0x10000u) ? 1536u : 0u;
        u32 dY = (pk & 0x20000u) ? 98304u : 0u;
        u32 o01 = o00 + dX, o10 = o00 + dY, o11 = o00 + dY + dX;
        u32x2 K00 = *(const u32x2*)(base + o00);
        u32x2 V00 = *(const u32x2*)(base + o00 + 512);
        u32x2 K01 = *(const u32x2*)(base + o01);
        u32x2 V01 = *(const u32x2*)(base + o01 + 512);
        u32x2 K10 = *(const u32x2*)(base + o10);
        u32x2 V10 = *(const u32x2*)(base + o10 + 512);
        u32x2 K11 = *(const u32x2*)(base + o11);
        u32x2 V11 = *(const u32x2*)(base + o11 + 512);
        float w00 = (1.f - wx) * (1.f - wy), w01 = wx * (1.f - wy);
        float w10 = (1.f - wx) * wy,         w11 = wx * wy;
        f32x2 ka = unpk2(K00.x) * w00 + unpk2(K01.x) * w01
                 + unpk2(K10.x) * w10 + unpk2(K11.x) * w11;
        f32x2 kb = unpk2(K00.y) * w00 + unpk2(K01.y) * w01
                 + unpk2(K10.y) * w10 + unpk2(K11.y) * w11;
        f32x2 vva = unpk2(V00.x) * w00 + unpk2(V01.x) * w01
                  + unpk2(V10.x) * w10 + unpk2(V11.x) * w11;
        f32x2 vvb = unpk2(V00.y) * w00 + unpk2(V01.y) * w01
                  + unpk2(V10.y) * w10 + unpk2(V11.y) * w11;
        f32x2 pr = qa * ka + qb * kb;
        float part = pr.x + pr.y;
        part += __shfl_xor(part, 4);
        part += __shfl_xor(part, 2);
        part += __shfl_xor(part, 1);
        logit[k_] = part * m;
        va[k_] = vva * m;
        vb[k_] = vvb * m;
    }
    float mx = fmaxf(fmaxf(fmaxf(logit[0], logit[1]), fmaxf(logit[2], logit[3])),
                     fmaxf(fmaxf(logit[4], logit[5]),
                           fmaxf(fmaxf(logit[6], logit[7]), logit[8])));
    float s = 0.f;
    #pragma unroll
    for (int k_ = 0; k_ < KPT; k_++) { logit[k_] = __expf(logit[k_] - mx); s += logit[k_]; }
    float inv = 1.f / s;
    f32x2 oa = {0.f, 0.f}, ob = {0.f, 0.f};
    #pragma unroll
    for (int k_ = 0; k_ < KPT; k_++) { oa += va[k_] * logit[k_]; ob += vb[k_] * logit[k_]; }
    oa *= inv; ob *= inv;
    u32x2 outw;
    outw.x = (u32)f2b(oa.x) | ((u32)f2b(oa.y) << 16);
    outw.y = (u32)f2b(ob.x) | ((u32)f2b(ob.y) << 16);
    *(u32x2*)&attn_b[(size_t)pix * 256 + c0] = outw;
}

extern "C" void kernel_launch(void* const* d_in, const int* in_sizes, int n_in,
                              void* d_out, int out_size, void* d_ws, size_t ws_size,
                              hipStream_t stream) {
    const float* x            = (const float*)d_in[0];
    const float* qkv_w        = (const float*)d_in[1];
    const float* qkv_b        = (const float*)d_in[2];
    const float* dw_w         = (const float*)d_in[3];
    const float* dw_b         = (const float*)d_in[4];
    const float* off_pconv_w  = (const float*)d_in[5];
    const float* off_w        = (const float*)d_in[6];
    const float* off_b        = (const float*)d_in[7];
    const float* mask_pconv_w = (const float*)d_in[8];
    const float* mask_w       = (const float*)d_in[9];
    const float* mask_b       = (const float*)d_in[10];
    const float* proj_w       = (const float*)d_in[11];
    const float* proj_b       = (const float*)d_in[12];

    char* ws = (char*)d_ws;
    size_t off = 0;
    u16*   qkv_wT_b   = (u16*)(ws + off);                 off += 768ull*256*2;
    u16*   proj_wT_b  = (u16*)(ws + off);                 off += 256ull*256*2;
    u16*   qkv_bf     = (u16*)(ws + off);                 off += 8192ull*768*2;
    u16*   qdw_b      = (u16*)(ws + off);                 off += 8192ull*768*2;
    u16*   cwT_b      = (u16*)(ws + off);                 off += 160ull*768*2;
    float* cb         = (float*)(ws + off);               off += 256*4;
    float* om0        = (float*)(ws + off);               off += 8192ull*160*4;
    float* om1        = (float*)(ws + off);               off += 8192ull*160*4;
    float* om2        = (float*)(ws + off);               off += 8192ull*160*4;
    float* om3        = (float*)(ws + off);               off += 8192ull*160*4;
    u16*   attn_b     = (u16*)(ws + off);                 off += 8192ull*256*2;

    // 1) weight convert/transpose + composite offset/mask weights (one launch)
    prep_weights<<<1792, 256, 0, stream>>>(qkv_w, proj_w, off_pconv_w, off_w, off_b,
                                           mask_pconv_w, mask_w, mask_b,
                                           qkv_wT_b, proj_wT_b, cwT_b, cb);
    // 2) qkv = x @ qkv_w + b   (fp32 A converted in staging, bf16 MFMA, bf16 out)
    mfma_gemm<true, true, 256><<<dim3(128, 12), 256, 0, stream>>>(x, qkv_wT_b, qkv_b,
                                                                  qkv_bf, 768);
    // 3) depthwise 3x3
    dwconv_b<<<3072, 256, 0, stream>>>(qkv_bf, dw_w, dw_b, qdw_b);
    // 4) offsets + mask (im2col MFMA, K-split x4 in one grid)
    offmask_mfma<<<1024, 256, 0, stream>>>(qdw_b, cwT_b, cb, om0, om1, om2, om3);
    // 5) deformable attention (point-params fused in-block; XCD-chunked swizzle)
    deform_attn<<<2048, 256, 0, stream>>>(qdw_b, om0, om1, om2, om3, attn_b);
    // 6) projection (fp32 out)
    mfma_gemm<false, false, 256><<<dim3(128, 4), 256, 0, stream>>>(attn_b, proj_wT_b,
                                                                   proj_b, d_out, 256);
}